// Round 7
// baseline (32026.917 us; speedup 1.0000x reference)
//
#include <hip/hip_runtime.h>
#include <hip/hip_bf16.h>
#include <stdint.h>

#define S_LEN 256
#define BATCH 64
#define HD 256
#define NT 9
#define NTOK (S_LEN*BATCH)   // 16384

typedef _Float16 hf2 __attribute__((ext_vector_type(2)));
typedef short bf16x8 __attribute__((ext_vector_type(8)));
typedef float f32x4 __attribute__((ext_vector_type(4)));

__device__ __forceinline__ float sigf(float x){ return 1.f/(1.f+__expf(-x)); }
__device__ __forceinline__ float tanh_(float x){ return 1.f - 2.f/(__expf(2.f*x)+1.f); }
__device__ __forceinline__ float wredsum(float v){
#pragma unroll
  for (int s = 32; s > 0; s >>= 1) v += __shfl_xor(v, s);
  return v;
}
__device__ __forceinline__ uint16_t f2b(float f){
  __hip_bfloat16 h = __float2bfloat16(f);
  return *(uint16_t*)&h;
}
__device__ __forceinline__ float b2f(uint16_t u){
  union{uint32_t i; float f;} a; a.i = ((uint32_t)u)<<16; return a.f;
}

__device__ __forceinline__ float dot2p(uint32_t w, uint32_t h, float acc){
#if __has_builtin(__builtin_amdgcn_fdot2)
  return __builtin_amdgcn_fdot2(__builtin_bit_cast(hf2, w), __builtin_bit_cast(hf2, h), acc, false);
#else
  hf2 wv = __builtin_bit_cast(hf2, w), hv = __builtin_bit_cast(hf2, h);
  return acc + (float)wv.x*(float)hv.x + (float)wv.y*(float)hv.y;
#endif
}

// ---- prep: wih16[n][k] = bf16(w_ih_dir[g][k]) (n = dir*1024+g); bias[n] = b_ih+b_hh ----
__global__ void prep2(const float* __restrict__ wihf, const float* __restrict__ wihb,
                      const float* __restrict__ bif, const float* __restrict__ bhf,
                      const float* __restrict__ bib, const float* __restrict__ bhb,
                      uint16_t* __restrict__ wih16, float* __restrict__ bias){
  int idx = blockIdx.x*256 + threadIdx.x;       // < 2048*256
  int n = idx >> 8;
  int k = idx & 255;
  const float* w = (n < 1024) ? wihf : wihb;
  int g = n & 1023;
  wih16[idx] = f2b(w[g*256 + k]);
  if (idx < 2048) {
    bias[idx] = (idx < 1024) ? (bif[idx] + bhf[idx]) : (bib[idx-1024] + bhb[idx-1024]);
  }
}

// ---- prep: pack w_hh for lstm5's (half, jc, ks) assignment; also zero sync flags ----
// tid = jc*8+ks (1024 threads/wg). Thread owns unit u = half*128+jc, all 4 gates,
// k-window [ks*32, ks*32+32) -> 16 pairs/gate, 64 pairs total (all VGPR-resident).
// wph[((dir*2+half)*64 + g*16 + p)*1024 + tid] = f16pair(w[g*256+u][ks*32+2p], +1)
__global__ void prep_wph4(const float* __restrict__ whf, const float* __restrict__ whb,
                          uint32_t* __restrict__ wph, int* __restrict__ flags){
  if (blockIdx.x == 0 && threadIdx.x < 256) flags[threadIdx.x] = 0;
  int idx = blockIdx.x*256 + threadIdx.x;       // < 262144
  int dh = idx >> 16;          // dir*2+half
  int dir = dh >> 1, half = dh & 1;
  int rem = idx & 65535;
  int r = rem >> 10;           // 0..63 = g*16+p
  int tid = rem & 1023;
  int g = r >> 4, p = r & 15;
  int jc = tid >> 3, ks = tid & 7;
  int u = half*128 + jc;
  const float* w = dir ? whb : whf;
  const float* row = w + (size_t)(g*256 + u)*256 + ks*32 + 2*p;
  _Float16 lo = (_Float16)row[0];
  _Float16 hi = (_Float16)row[1];
  uint16_t l16 = __builtin_bit_cast(uint16_t, lo);
  uint16_t h16 = __builtin_bit_cast(uint16_t, hi);
  wph[idx] = (uint32_t)l16 | ((uint32_t)h16 << 16);
}

// ---- input projection via MFMA: xg[m][j*4+g] = emb[tok(m)] . w_ih[n] + bias[n] ----
__global__ __launch_bounds__(256) void inproj_mfma(const int* __restrict__ inp,
    const float* __restrict__ emb, const uint16_t* __restrict__ wih16,
    const float* __restrict__ bias, uint16_t* __restrict__ xgf,
    uint16_t* __restrict__ xgb){
  __shared__ uint16_t As[64][72];    // A[m][k] bf16, +8 pad
  __shared__ uint16_t Bs[128][72];   // B^T[c][k] = w_ih[n0+c][k] bf16, +8 pad
  __shared__ int toks[64];
  int bm = blockIdx.x, bn = blockIdx.y;
  int tid = threadIdx.x;
  if (tid < 64) {
    int m = bm*64 + tid;                       // b = m&63, t = m>>6
    toks[tid] = inp[(m & 63)*S_LEN + (m >> 6)];
  }
  __syncthreads();
  int w = tid >> 6, l = tid & 63;
  int lr = l & 15, lg = l >> 4;
  f32x4 acc[8];
#pragma unroll
  for (int cf = 0; cf < 8; ++cf) acc[cf] = (f32x4){0.f,0.f,0.f,0.f};

  int am = tid >> 2, aq = tid & 3;             // A staging: row am, 16 k each
  int bc = tid >> 1, bh = tid & 1;             // B staging: row bc, 32 k each

  for (int k0 = 0; k0 < 256; k0 += 64) {
    {
      const float* asrc = emb + (size_t)toks[am]*256 + k0 + aq*16;
      float4 v0 = *(const float4*)(asrc+0);
      float4 v1 = *(const float4*)(asrc+4);
      float4 v2 = *(const float4*)(asrc+8);
      float4 v3 = *(const float4*)(asrc+12);
      uint16_t t16[16];
      t16[0]=f2b(v0.x); t16[1]=f2b(v0.y); t16[2]=f2b(v0.z); t16[3]=f2b(v0.w);
      t16[4]=f2b(v1.x); t16[5]=f2b(v1.y); t16[6]=f2b(v1.z); t16[7]=f2b(v1.w);
      t16[8]=f2b(v2.x); t16[9]=f2b(v2.y); t16[10]=f2b(v2.z); t16[11]=f2b(v2.w);
      t16[12]=f2b(v3.x); t16[13]=f2b(v3.y); t16[14]=f2b(v3.z); t16[15]=f2b(v3.w);
      *(uint4*)&As[am][aq*16]     = *(uint4*)&t16[0];
      *(uint4*)&As[am][aq*16 + 8] = *(uint4*)&t16[8];
    }
    {
      const uint16_t* bsrc = wih16 + (size_t)(bn*128 + bc)*256 + k0 + bh*32;
      uint4 b0 = *(const uint4*)(bsrc+0);
      uint4 b1 = *(const uint4*)(bsrc+8);
      uint4 b2 = *(const uint4*)(bsrc+16);
      uint4 b3 = *(const uint4*)(bsrc+24);
      *(uint4*)&Bs[bc][bh*32+0]  = b0;
      *(uint4*)&Bs[bc][bh*32+8]  = b1;
      *(uint4*)&Bs[bc][bh*32+16] = b2;
      *(uint4*)&Bs[bc][bh*32+24] = b3;
    }
    __syncthreads();
#pragma unroll
    for (int ks = 0; ks < 2; ++ks) {
      int koff = ks*32 + lg*8;
      bf16x8 a = *(const bf16x8*)&As[16*w + lr][koff];
#pragma unroll
      for (int cf = 0; cf < 8; ++cf) {
        bf16x8 b = *(const bf16x8*)&Bs[cf*16 + lr][koff];
        acc[cf] = __builtin_amdgcn_mfma_f32_16x16x32_bf16(a, b, acc[cf], 0, 0, 0);
      }
    }
    __syncthreads();
  }
  int n0 = bn*128;
  bool back = (n0 >= 1024);
  uint16_t* dst = back ? xgb : xgf;
  int nb0 = back ? (n0 - 1024) : n0;
#pragma unroll
  for (int cf = 0; cf < 8; ++cf) {
    int nc = cf*16 + lr;
    int nd = nb0 + nc;                 // within-dir column
    int gj = (nd & 255)*4 + (nd >> 8); // unit-major, gate-minor position
    float bv = bias[n0 + nc];
#pragma unroll
    for (int r = 0; r < 4; ++r) {
      int m = bm*64 + 16*w + lg*4 + r;
      dst[(size_t)m*1024 + gj] = f2b(acc[cf][r] + bv);
    }
  }
}

// ---- recurrence: 256 wgs = (half in [0,2)) x (chain c = dir*64+b in [0,128)) ----
// wg owns 128 hidden units (half*128..+128) of its chain; 1024 threads = jc*8+ks.
// Thread: unit u = half*128+jc, all 4 gates, k-window [ks*32,+32): 64 VGPR pairs.
// Per step: h-window from own LDS (if window in own half) or partner's global
// slice (release/acquire flag sync, double-buffered). 8-lane shfl z-reduce.
__global__ __launch_bounds__(1024, 4)
void lstm5(const uint32_t* __restrict__ wph,
    const uint16_t* __restrict__ xgf, const uint16_t* __restrict__ xgb,
    __hip_bfloat16* __restrict__ hout,
    _Float16* __restrict__ hx, int* flags){
  int bid = blockIdx.x;
  int half = bid >> 7;
  int c = bid & 127;            // chain id; wgs c and c+128 pair (same XCD mod 8)
  int dir = c >> 6;
  int b = c & 63;
  int tid = threadIdx.x;
  int jc = tid >> 3, ks = tid & 7;
  int u = half*128 + jc;
  __shared__ __align__(16) _Float16 hs[2][128];   // own half, double-buffered

  const uint32_t* wp = wph + (size_t)((dir*2 + half)*64)*1024 + tid;
  uint32_t wreg[64];
#pragma unroll
  for (int r = 0; r < 64; ++r) wreg[r] = wp[(size_t)r*1024];
#pragma unroll
  for (int r = 0; r < 64; ++r) asm volatile("" : "+v"(wreg[r]));
  asm volatile("" ::: "memory");

  const uint16_t* xgp = (dir ? xgb : xgf) + (size_t)b*1024 + u*4;
  bool ownside = ((ks >> 2) == half);   // my k-window lies in my own half
  int q32 = ks & 3;                     // 32-elem window within that half
  int* myflag = flags + c*2 + half;
  int* pflag  = flags + c*2 + (half^1);
  float cc = 0.f;

  for (int t = 0; t < S_LEN; ++t) {
    int ts = dir ? (S_LEN-1-t) : t;
    uint2 xq = *(const uint2*)(xgp + (size_t)ts*65536);
    float z0 = 0.f, z1 = 0.f, z2 = 0.f, z3 = 0.f;
    if (t) {
      uint32_t hw[16];
      if (ownside) {
        const uint4* hp = (const uint4*)&hs[t & 1][q32*32];
        uint4 a0 = hp[0], a1 = hp[1], a2 = hp[2], a3 = hp[3];
        *(uint4*)&hw[0]  = a0; *(uint4*)&hw[4]  = a1;
        *(uint4*)&hw[8]  = a2; *(uint4*)&hw[12] = a3;
      } else {
        while (__hip_atomic_load(pflag, __ATOMIC_ACQUIRE, __HIP_MEMORY_SCOPE_AGENT) < t) {}
        const uint4* hp = (const uint4*)(hx + ((size_t)(c*2 + (t & 1))*2 + (half^1))*128 + q32*32);
        uint4 a0 = hp[0], a1 = hp[1], a2 = hp[2], a3 = hp[3];
        *(uint4*)&hw[0]  = a0; *(uint4*)&hw[4]  = a1;
        *(uint4*)&hw[8]  = a2; *(uint4*)&hw[12] = a3;
      }
#pragma unroll
      for (int p = 0; p < 16; ++p) {
        z0 = dot2p(wreg[p],      hw[p], z0);
        z1 = dot2p(wreg[16 + p], hw[p], z1);
        z2 = dot2p(wreg[32 + p], hw[p], z2);
        z3 = dot2p(wreg[48 + p], hw[p], z3);
      }
      // reduce the 8 k-window partials (lanes ks = 0..7 within each octet)
#pragma unroll
      for (int off = 1; off <= 4; off <<= 1) {
        z0 += __shfl_xor(z0, off);
        z1 += __shfl_xor(z1, off);
        z2 += __shfl_xor(z2, off);
        z3 += __shfl_xor(z3, off);
      }
    }
    z0 += b2f((uint16_t)(xq.x & 0xffff));
    z1 += b2f((uint16_t)(xq.x >> 16));
    z2 += b2f((uint16_t)(xq.y & 0xffff));
    z3 += b2f((uint16_t)(xq.y >> 16));
    float ig = sigf(z0), fg = sigf(z1), gg = tanh_(z2), og = sigf(z3);
    cc = fg*cc + ig*gg;
    float hj = og * tanh_(cc);
    if (ks == 0) {
      int nxt = (t & 1) ^ 1;
      hs[nxt][jc] = (_Float16)hj;
      hx[((size_t)(c*2 + nxt)*2 + half)*128 + jc] = (_Float16)hj;
      hout[((size_t)ts*BATCH + b)*512 + dir*256 + u] = __float2bfloat16(hj);
      __threadfence();
    }
    __syncthreads();
    if (tid == 0)
      __hip_atomic_store(myflag, t + 1, __ATOMIC_RELEASE, __HIP_MEMORY_SCOPE_AGENT);
  }
}

// ---- output projection: emissions[t*64+b][j] = h . w_out[j+1] + b_out[j+1] ----
__global__ __launch_bounds__(256) void outproj(const __hip_bfloat16* __restrict__ hb,
    const float* __restrict__ w_out, const float* __restrict__ b_out,
    float* __restrict__ em){
  __shared__ float wsm[NT*512];
  __shared__ float bsm[NT];
  int tid = threadIdx.x;
  for (int i = tid; i < NT*512; i += 256) wsm[i] = w_out[512 + i];  // rows 1..9
  if (tid < NT) bsm[tid] = b_out[1 + tid];
  __syncthreads();
  int wave = tid >> 6, l = tid & 63;
  int m = blockIdx.x*4 + wave;
  const __hip_bfloat16* hp = hb + (size_t)m*512;
  float hv[8];
#pragma unroll
  for (int q = 0; q < 8; ++q) hv[q] = __bfloat162float(hp[l + 64*q]);
  for (int jj = 0; jj < NT; ++jj) {
    float p = 0.f;
#pragma unroll
    for (int q = 0; q < 8; ++q) p += hv[q]*wsm[jj*512 + 64*q + l];
    p = wredsum(p);
    if (l == 0) em[(size_t)m*NT + jj] = p + bsm[jj];
  }
}

// ---- CRF: one wave per batch item; lanes 0..8 hold the 9-state score ----
__global__ __launch_bounds__(64) void crf(const int* __restrict__ tags,
    const float* __restrict__ em, const float* __restrict__ start_t,
    const float* __restrict__ end_t, const float* __restrict__ trans,
    float* __restrict__ part){
  int b = blockIdx.x;
  int l = threadIdx.x;
  float np = 0.f;
  for (int t = l; t < S_LEN; t += 64) {
    int tg = tags[b*S_LEN + t] - 1;
    float e = em[(size_t)(t*BATCH + b)*NT + tg];
    float tr = (t == 0) ? start_t[tg] : trans[(tags[b*S_LEN + t - 1] - 1)*NT + tg];
    np += e + tr;
  }
  float num = wredsum(np);
  num += end_t[tags[b*S_LEN + S_LEN-1] - 1];
  int j = (l < NT) ? l : 0;
  float tj[NT];
#pragma unroll
  for (int i = 0; i < NT; ++i) tj[i] = trans[i*NT + j];
  float sc = start_t[j] + em[(size_t)b*NT + j];
  for (int t = 1; t < S_LEN; ++t) {
    float e = em[(size_t)(t*BATCH + b)*NT + j];
    float m = -1e30f;
    float vals[NT];
#pragma unroll
    for (int i = 0; i < NT; ++i) { float si = __shfl(sc, i); vals[i] = si + tj[i]; m = fmaxf(m, vals[i]); }
    float ssum = 0.f;
#pragma unroll
    for (int i = 0; i < NT; ++i) ssum += __expf(vals[i] - m);
    sc = e + m + __logf(ssum);
  }
  float vj = (l < NT) ? (sc + end_t[l]) : -1e30f;
  float mx = vj;
#pragma unroll
  for (int s2 = 32; s2 > 0; s2 >>= 1) mx = fmaxf(mx, __shfl_xor(mx, s2));
  float es = __expf(vj - mx);
  es = wredsum(es);
  if (l == 0) part[b] = num - (mx + __logf(es));
}

__global__ void finalize(const float* __restrict__ part, float* __restrict__ out){
  float v = part[threadIdx.x];
  v = wredsum(v);
  if (threadIdx.x == 0) out[0] = -(v / 64.f);
}

extern "C" void kernel_launch(void* const* d_in, const int* in_sizes, int n_in,
                              void* d_out, int out_size, void* d_ws, size_t ws_size,
                              hipStream_t stream) {
  (void)in_sizes; (void)n_in; (void)out_size; (void)ws_size;
  const int*   inputs  = (const int*)d_in[0];
  const int*   tags    = (const int*)d_in[1];
  const float* emb     = (const float*)d_in[3];
  const float* w_ih_f  = (const float*)d_in[4];
  const float* w_hh_f  = (const float*)d_in[5];
  const float* b_ih_f  = (const float*)d_in[6];
  const float* b_hh_f  = (const float*)d_in[7];
  const float* w_ih_b  = (const float*)d_in[8];
  const float* w_hh_b  = (const float*)d_in[9];
  const float* b_ih_b  = (const float*)d_in[10];
  const float* b_hh_b  = (const float*)d_in[11];
  const float* w_out   = (const float*)d_in[12];
  const float* b_out   = (const float*)d_in[13];
  const float* start_t = (const float*)d_in[14];
  const float* end_t   = (const float*)d_in[15];
  const float* trans   = (const float*)d_in[16];

  char* ws = (char*)d_ws;
  size_t off = 0;
  auto alloc = [&](size_t bytes) -> void* {
    void* p = ws + off;
    off = (off + bytes + 255) & ~(size_t)255;
    return p;
  };
  uint16_t* xgf = (uint16_t*)alloc((size_t)NTOK*1024*2);
  uint16_t* xgb = (uint16_t*)alloc((size_t)NTOK*1024*2);
  __hip_bfloat16* hbf = (__hip_bfloat16*)alloc((size_t)NTOK*512*2);
  float*    em    = (float*)alloc((size_t)NTOK*NT*4);
  uint16_t* wih16 = (uint16_t*)alloc((size_t)2048*256*2);
  float*    bias  = (float*)alloc((size_t)2048*4);
  uint32_t* wph   = (uint32_t*)alloc((size_t)2*2*64*1024*4);
  _Float16* hx    = (_Float16*)alloc((size_t)128*2*2*128*2);
  int*      flags = (int*)alloc((size_t)256*4);
  float*    part  = (float*)alloc((size_t)64*4);

  prep2<<<2048, 256, 0, stream>>>(w_ih_f, w_ih_b, b_ih_f, b_hh_f, b_ih_b, b_hh_b, wih16, bias);
  prep_wph4<<<1024, 256, 0, stream>>>(w_hh_f, w_hh_b, wph, flags);
  inproj_mfma<<<dim3(256, 16), 256, 0, stream>>>(inputs, emb, wih16, bias, xgf, xgb);
  lstm5<<<256, 1024, 0, stream>>>(wph, xgf, xgb, hbf, hx, flags);
  outproj<<<4096, 256, 0, stream>>>(hbf, w_out, b_out, em);
  crf<<<64, 64, 0, stream>>>(tags, em, start_t, end_t, trans, part);
  finalize<<<1, 64, 0, stream>>>(part, (float*)d_out);
}

// Round 8
// 1396.809 us; speedup vs baseline: 22.9286x; 22.9286x over previous
//
#include <hip/hip_runtime.h>
#include <hip/hip_bf16.h>
#include <stdint.h>

#define S_LEN 256
#define BATCH 64
#define HD 256
#define NT 9
#define NTOK (S_LEN*BATCH)   // 16384

typedef _Float16 hf2 __attribute__((ext_vector_type(2)));
typedef short bf16x8 __attribute__((ext_vector_type(8)));
typedef float f32x4 __attribute__((ext_vector_type(4)));

__device__ __forceinline__ float sigf(float x){ return 1.f/(1.f+__expf(-x)); }
__device__ __forceinline__ float tanh_(float x){ return 1.f - 2.f/(__expf(2.f*x)+1.f); }
__device__ __forceinline__ float wredsum(float v){
#pragma unroll
  for (int s = 32; s > 0; s >>= 1) v += __shfl_xor(v, s);
  return v;
}
__device__ __forceinline__ uint16_t f2b(float f){
  __hip_bfloat16 h = __float2bfloat16(f);
  return *(uint16_t*)&h;
}
__device__ __forceinline__ float b2f(uint16_t u){
  union{uint32_t i; float f;} a; a.i = ((uint32_t)u)<<16; return a.f;
}

__device__ __forceinline__ float dot2p(uint32_t w, uint32_t h, float acc){
#if __has_builtin(__builtin_amdgcn_fdot2)
  return __builtin_amdgcn_fdot2(__builtin_bit_cast(hf2, w), __builtin_bit_cast(hf2, h), acc, false);
#else
  hf2 wv = __builtin_bit_cast(hf2, w), hv = __builtin_bit_cast(hf2, h);
  return acc + (float)wv.x*(float)hv.x + (float)wv.y*(float)hv.y;
#endif
}

// ---- prep: wih16[n][k] = bf16(w_ih_dir[g][k]) (n = dir*1024+g); bias[n] = b_ih+b_hh ----
__global__ void prep2(const float* __restrict__ wihf, const float* __restrict__ wihb,
                      const float* __restrict__ bif, const float* __restrict__ bhf,
                      const float* __restrict__ bib, const float* __restrict__ bhb,
                      uint16_t* __restrict__ wih16, float* __restrict__ bias){
  int idx = blockIdx.x*256 + threadIdx.x;       // < 2048*256
  int n = idx >> 8;
  int k = idx & 255;
  const float* w = (n < 1024) ? wihf : wihb;
  int g = n & 1023;
  wih16[idx] = f2b(w[g*256 + k]);
  if (idx < 2048) {
    bias[idx] = (idx < 1024) ? (bif[idx] + bhf[idx]) : (bib[idx-1024] + bhb[idx-1024]);
  }
}

// ---- prep: pack w_hh for lstm6's (j2, ks) assignment ----
// tid = j2*8+ks (1024 threads). Thread owns 8 cols c = g*2+u_loc (units 2j2,2j2+1
// x 4 gates), k-window [ks*32, +32) -> 16 pairs/col, 128 pairs total (all reg-resident).
// wph[(dir*128 + c*16 + p)*1024 + tid] = f16pair(w[g*256+u][ks*32+2p], [..+1])
__global__ void prep_wph5(const float* __restrict__ whf, const float* __restrict__ whb,
                          uint32_t* __restrict__ wph){
  int idx = blockIdx.x*256 + threadIdx.x;       // < 2*128*1024
  int dir = idx >> 17;
  int rem = idx & 131071;
  int r = rem >> 10;        // 0..127 = c*16 + p
  int tid = rem & 1023;
  int c = r >> 4, p = r & 15;
  int g = c >> 1;
  int j2 = tid >> 3, ks = tid & 7;
  int u = 2*j2 + (c & 1);
  const float* w = dir ? whb : whf;
  const float* row = w + (size_t)(g*256 + u)*256 + ks*32 + 2*p;
  _Float16 lo = (_Float16)row[0];
  _Float16 hi = (_Float16)row[1];
  uint16_t l16 = __builtin_bit_cast(uint16_t, lo);
  uint16_t h16 = __builtin_bit_cast(uint16_t, hi);
  wph[idx] = (uint32_t)l16 | ((uint32_t)h16 << 16);
}

// ---- input projection via MFMA: xg[m][u*4+g] = emb[tok(m)] . w_ih[n] + bias[n] ----
__global__ __launch_bounds__(256) void inproj_mfma(const int* __restrict__ inp,
    const float* __restrict__ emb, const uint16_t* __restrict__ wih16,
    const float* __restrict__ bias, uint16_t* __restrict__ xgf,
    uint16_t* __restrict__ xgb){
  __shared__ uint16_t As[64][72];    // A[m][k] bf16, +8 pad
  __shared__ uint16_t Bs[128][72];   // B^T[c][k] = w_ih[n0+c][k] bf16, +8 pad
  __shared__ int toks[64];
  int bm = blockIdx.x, bn = blockIdx.y;
  int tid = threadIdx.x;
  if (tid < 64) {
    int m = bm*64 + tid;                       // b = m&63, t = m>>6
    toks[tid] = inp[(m & 63)*S_LEN + (m >> 6)];
  }
  __syncthreads();
  int w = tid >> 6, l = tid & 63;
  int lr = l & 15, lg = l >> 4;
  f32x4 acc[8];
#pragma unroll
  for (int cf = 0; cf < 8; ++cf) acc[cf] = (f32x4){0.f,0.f,0.f,0.f};

  int am = tid >> 2, aq = tid & 3;             // A staging: row am, 16 k each
  int bc = tid >> 1, bh = tid & 1;             // B staging: row bc, 32 k each

  for (int k0 = 0; k0 < 256; k0 += 64) {
    {
      const float* asrc = emb + (size_t)toks[am]*256 + k0 + aq*16;
      float4 v0 = *(const float4*)(asrc+0);
      float4 v1 = *(const float4*)(asrc+4);
      float4 v2 = *(const float4*)(asrc+8);
      float4 v3 = *(const float4*)(asrc+12);
      uint16_t t16[16];
      t16[0]=f2b(v0.x); t16[1]=f2b(v0.y); t16[2]=f2b(v0.z); t16[3]=f2b(v0.w);
      t16[4]=f2b(v1.x); t16[5]=f2b(v1.y); t16[6]=f2b(v1.z); t16[7]=f2b(v1.w);
      t16[8]=f2b(v2.x); t16[9]=f2b(v2.y); t16[10]=f2b(v2.z); t16[11]=f2b(v2.w);
      t16[12]=f2b(v3.x); t16[13]=f2b(v3.y); t16[14]=f2b(v3.z); t16[15]=f2b(v3.w);
      *(uint4*)&As[am][aq*16]     = *(uint4*)&t16[0];
      *(uint4*)&As[am][aq*16 + 8] = *(uint4*)&t16[8];
    }
    {
      const uint16_t* bsrc = wih16 + (size_t)(bn*128 + bc)*256 + k0 + bh*32;
      uint4 b0 = *(const uint4*)(bsrc+0);
      uint4 b1 = *(const uint4*)(bsrc+8);
      uint4 b2 = *(const uint4*)(bsrc+16);
      uint4 b3 = *(const uint4*)(bsrc+24);
      *(uint4*)&Bs[bc][bh*32+0]  = b0;
      *(uint4*)&Bs[bc][bh*32+8]  = b1;
      *(uint4*)&Bs[bc][bh*32+16] = b2;
      *(uint4*)&Bs[bc][bh*32+24] = b3;
    }
    __syncthreads();
#pragma unroll
    for (int ks = 0; ks < 2; ++ks) {
      int koff = ks*32 + lg*8;
      bf16x8 a = *(const bf16x8*)&As[16*w + lr][koff];
#pragma unroll
      for (int cf = 0; cf < 8; ++cf) {
        bf16x8 b = *(const bf16x8*)&Bs[cf*16 + lr][koff];
        acc[cf] = __builtin_amdgcn_mfma_f32_16x16x32_bf16(a, b, acc[cf], 0, 0, 0);
      }
    }
    __syncthreads();
  }
  int n0 = bn*128;
  bool back = (n0 >= 1024);
  uint16_t* dst = back ? xgb : xgf;
  int nb0 = back ? (n0 - 1024) : n0;
#pragma unroll
  for (int cf = 0; cf < 8; ++cf) {
    int nc = cf*16 + lr;
    int nd = nb0 + nc;                 // within-dir column
    int gj = (nd & 255)*4 + (nd >> 8); // unit-major, gate-minor position
    float bv = bias[n0 + nc];
#pragma unroll
    for (int r = 0; r < 4; ++r) {
      int m = bm*64 + 16*w + lg*4 + r;
      dst[(size_t)m*1024 + gj] = f2b(acc[cf][r] + bv);
    }
  }
}

// ---- recurrence: one wg per (dir, batch); 1024 threads = (j2 in [0,128)) x (ks in [0,8)) ----
// Thread: units {2j2, 2j2+1} x 4 gates over k-window [32ks, +32): 128 reg-resident pairs,
// ZERO LDS weight reads. h in LDS as 8 skewed 32-half windows (80B stride: banks
// 0,20,8,28,16,4,24,12 -> conflict-free 8-way broadcast). 3-round octet shfl z-reduce,
// redundant pointwise on all lanes, 1 barrier/step. 16 waves/wg = 4/SIMD latency hiding.
__global__ __launch_bounds__(1024, 4)
void lstm6(const uint32_t* __restrict__ wph,
    const uint16_t* __restrict__ xgf, const uint16_t* __restrict__ xgb,
    __hip_bfloat16* __restrict__ hout){
  int dir = blockIdx.x >> 6;
  int b = blockIdx.x & 63;
  int tid = threadIdx.x;
  int j2 = tid >> 3, ks = tid & 7;
  __shared__ __align__(16) _Float16 hs[2][8][40];   // 1.28 KB, skewed windows

  const uint32_t* wp = wph + (size_t)dir*131072 + tid;
  uint32_t wreg[128];
#pragma unroll
  for (int r = 0; r < 128; ++r) wreg[r] = wp[(size_t)r*1024];
#pragma unroll
  for (int r = 0; r < 128; ++r) asm volatile("" : "+v"(wreg[r]));
  asm volatile("" ::: "memory");

  if (tid < 320) ((_Float16*)hs)[tid] = (_Float16)0.f;   // zero hs[0]
  float c0 = 0.f, c1 = 0.f;
  const uint16_t* xgp = (dir ? xgb : xgf) + (size_t)b*1024 + j2*8;
  __syncthreads();

  int ts0 = dir ? (S_LEN-1) : 0;
  uint4 xq = *(const uint4*)(xgp + (size_t)ts0*65536);
  for (int t = 0; t < S_LEN; ++t) {
    int ts = dir ? (S_LEN-1-t) : t;
    int cur = t & 1;
    // prefetch next step's x (hidden under the dot loop)
    uint4 xnext = xq;
    if (t + 1 < S_LEN) {
      int tn = dir ? (S_LEN-2-t) : (t+1);
      xnext = *(const uint4*)(xgp + (size_t)tn*65536);
    }
    float zc[8] = {0.f,0.f,0.f,0.f,0.f,0.f,0.f,0.f};
    const uint4* hp = (const uint4*)&hs[cur][ks][0];
#pragma unroll
    for (int qq = 0; qq < 4; ++qq) {
      uint4 hq = hp[qq];
#pragma unroll
      for (int cc = 0; cc < 8; ++cc) {
        zc[cc] = dot2p(wreg[cc*16 + qq*4 + 0], hq.x, zc[cc]);
        zc[cc] = dot2p(wreg[cc*16 + qq*4 + 1], hq.y, zc[cc]);
        zc[cc] = dot2p(wreg[cc*16 + qq*4 + 2], hq.z, zc[cc]);
        zc[cc] = dot2p(wreg[cc*16 + qq*4 + 3], hq.w, zc[cc]);
      }
    }
    // reduce the 8 k-window partials (lanes ks = 0..7 within each octet)
#pragma unroll
    for (int cc = 0; cc < 8; ++cc) zc[cc] += __shfl_xor(zc[cc], 1);
#pragma unroll
    for (int cc = 0; cc < 8; ++cc) zc[cc] += __shfl_xor(zc[cc], 2);
#pragma unroll
    for (int cc = 0; cc < 8; ++cc) zc[cc] += __shfl_xor(zc[cc], 4);
    // add x: layout [u][g], col c = g*2+u -> xh[(c&1)*4 + (c>>1)]
    uint16_t xh[8];
    *(uint4*)xh = xq;
#pragma unroll
    for (int cc = 0; cc < 8; ++cc) zc[cc] += b2f(xh[(cc & 1)*4 + (cc >> 1)]);
    // pointwise, both units (redundant across the 8 ks lanes)
    float ig0 = sigf(zc[0]), fg0 = sigf(zc[2]), gg0 = tanh_(zc[4]), og0 = sigf(zc[6]);
    c0 = fg0*c0 + ig0*gg0;
    float h0 = og0 * tanh_(c0);
    float ig1 = sigf(zc[1]), fg1 = sigf(zc[3]), gg1 = tanh_(zc[5]), og1 = sigf(zc[7]);
    c1 = fg1*c1 + ig1*gg1;
    float h1 = og1 * tanh_(c1);
    if (ks == 0) {
      // units 2j2, 2j2+1 -> window j2>>4, pair j2&15
      hf2 hpair; hpair.x = (_Float16)h0; hpair.y = (_Float16)h1;
      *(uint32_t*)&hs[cur^1][j2 >> 4][(j2 & 15)*2] = __builtin_bit_cast(uint32_t, hpair);
      uint32_t hb = (uint32_t)f2b(h0) | ((uint32_t)f2b(h1) << 16);
      *(uint32_t*)&hout[((size_t)ts*BATCH + b)*512 + dir*256 + 2*j2] = hb;
    }
    xq = xnext;
    __syncthreads();
  }
}

// ---- output projection: emissions[t*64+b][j] = h . w_out[j+1] + b_out[j+1] ----
__global__ __launch_bounds__(256) void outproj(const __hip_bfloat16* __restrict__ hb,
    const float* __restrict__ w_out, const float* __restrict__ b_out,
    float* __restrict__ em){
  __shared__ float wsm[NT*512];
  __shared__ float bsm[NT];
  int tid = threadIdx.x;
  for (int i = tid; i < NT*512; i += 256) wsm[i] = w_out[512 + i];  // rows 1..9
  if (tid < NT) bsm[tid] = b_out[1 + tid];
  __syncthreads();
  int wave = tid >> 6, l = tid & 63;
  int m = blockIdx.x*4 + wave;
  const __hip_bfloat16* hp = hb + (size_t)m*512;
  float hv[8];
#pragma unroll
  for (int q = 0; q < 8; ++q) hv[q] = __bfloat162float(hp[l + 64*q]);
  for (int jj = 0; jj < NT; ++jj) {
    float p = 0.f;
#pragma unroll
    for (int q = 0; q < 8; ++q) p += hv[q]*wsm[jj*512 + 64*q + l];
    p = wredsum(p);
    if (l == 0) em[(size_t)m*NT + jj] = p + bsm[jj];
  }
}

// ---- CRF: one wave per batch item; lanes 0..8 hold the 9-state score ----
__global__ __launch_bounds__(64) void crf(const int* __restrict__ tags,
    const float* __restrict__ em, const float* __restrict__ start_t,
    const float* __restrict__ end_t, const float* __restrict__ trans,
    float* __restrict__ part){
  int b = blockIdx.x;
  int l = threadIdx.x;
  float np = 0.f;
  for (int t = l; t < S_LEN; t += 64) {
    int tg = tags[b*S_LEN + t] - 1;
    float e = em[(size_t)(t*BATCH + b)*NT + tg];
    float tr = (t == 0) ? start_t[tg] : trans[(tags[b*S_LEN + t - 1] - 1)*NT + tg];
    np += e + tr;
  }
  float num = wredsum(np);
  num += end_t[tags[b*S_LEN + S_LEN-1] - 1];
  int j = (l < NT) ? l : 0;
  float tj[NT];
#pragma unroll
  for (int i = 0; i < NT; ++i) tj[i] = trans[i*NT + j];
  float sc = start_t[j] + em[(size_t)b*NT + j];
  for (int t = 1; t < S_LEN; ++t) {
    float e = em[(size_t)(t*BATCH + b)*NT + j];
    float m = -1e30f;
    float vals[NT];
#pragma unroll
    for (int i = 0; i < NT; ++i) { float si = __shfl(sc, i); vals[i] = si + tj[i]; m = fmaxf(m, vals[i]); }
    float ssum = 0.f;
#pragma unroll
    for (int i = 0; i < NT; ++i) ssum += __expf(vals[i] - m);
    sc = e + m + __logf(ssum);
  }
  float vj = (l < NT) ? (sc + end_t[l]) : -1e30f;
  float mx = vj;
#pragma unroll
  for (int s2 = 32; s2 > 0; s2 >>= 1) mx = fmaxf(mx, __shfl_xor(mx, s2));
  float es = __expf(vj - mx);
  es = wredsum(es);
  if (l == 0) part[b] = num - (mx + __logf(es));
}

__global__ void finalize(const float* __restrict__ part, float* __restrict__ out){
  float v = part[threadIdx.x];
  v = wredsum(v);
  if (threadIdx.x == 0) out[0] = -(v / 64.f);
}

extern "C" void kernel_launch(void* const* d_in, const int* in_sizes, int n_in,
                              void* d_out, int out_size, void* d_ws, size_t ws_size,
                              hipStream_t stream) {
  (void)in_sizes; (void)n_in; (void)out_size; (void)ws_size;
  const int*   inputs  = (const int*)d_in[0];
  const int*   tags    = (const int*)d_in[1];
  const float* emb     = (const float*)d_in[3];
  const float* w_ih_f  = (const float*)d_in[4];
  const float* w_hh_f  = (const float*)d_in[5];
  const float* b_ih_f  = (const float*)d_in[6];
  const float* b_hh_f  = (const float*)d_in[7];
  const float* w_ih_b  = (const float*)d_in[8];
  const float* w_hh_b  = (const float*)d_in[9];
  const float* b_ih_b  = (const float*)d_in[10];
  const float* b_hh_b  = (const float*)d_in[11];
  const float* w_out   = (const float*)d_in[12];
  const float* b_out   = (const float*)d_in[13];
  const float* start_t = (const float*)d_in[14];
  const float* end_t   = (const float*)d_in[15];
  const float* trans   = (const float*)d_in[16];

  char* ws = (char*)d_ws;
  size_t off = 0;
  auto alloc = [&](size_t bytes) -> void* {
    void* p = ws + off;
    off = (off + bytes + 255) & ~(size_t)255;
    return p;
  };
  uint16_t* xgf = (uint16_t*)alloc((size_t)NTOK*1024*2);
  uint16_t* xgb = (uint16_t*)alloc((size_t)NTOK*1024*2);
  __hip_bfloat16* hbf = (__hip_bfloat16*)alloc((size_t)NTOK*512*2);
  float*    em    = (float*)alloc((size_t)NTOK*NT*4);
  uint16_t* wih16 = (uint16_t*)alloc((size_t)2048*256*2);
  float*    bias  = (float*)alloc((size_t)2048*4);
  uint32_t* wph   = (uint32_t*)alloc((size_t)2*128*1024*4);
  float*    part  = (float*)alloc((size_t)64*4);

  prep2<<<2048, 256, 0, stream>>>(w_ih_f, w_ih_b, b_ih_f, b_hh_f, b_ih_b, b_hh_b, wih16, bias);
  prep_wph5<<<1024, 256, 0, stream>>>(w_hh_f, w_hh_b, wph);
  inproj_mfma<<<dim3(256, 16), 256, 0, stream>>>(inputs, emb, wih16, bias, xgf, xgb);
  lstm6<<<128, 1024, 0, stream>>>(wph, xgf, xgb, hbf);
  outproj<<<4096, 256, 0, stream>>>(hbf, w_out, b_out, em);
  crf<<<64, 64, 0, stream>>>(tags, em, start_t, end_t, trans, part);
  finalize<<<1, 64, 0, stream>>>(part, (float*)d_out);
}

// Round 9
// 1176.880 us; speedup vs baseline: 27.2134x; 1.1869x over previous
//
#include <hip/hip_runtime.h>
#include <hip/hip_bf16.h>
#include <stdint.h>

#define S_LEN 256
#define BATCH 64
#define HD 256
#define NT 9
#define NTOK (S_LEN*BATCH)   // 16384

#define NREG 192             // w_hh pairs in VGPRs/AGPRs per thread (cols 0..5)
#define NWL 16               // uint4 LDS rows (64 pairs: col6 rows 0..7, col7 rows 8..15)

typedef _Float16 hf2 __attribute__((ext_vector_type(2)));
typedef short bf16x8 __attribute__((ext_vector_type(8)));
typedef float f32x4 __attribute__((ext_vector_type(4)));

__device__ __forceinline__ float sigf(float x){ return 1.f/(1.f+__expf(-x)); }
__device__ __forceinline__ float tanh_(float x){ return 1.f - 2.f/(__expf(2.f*x)+1.f); }
__device__ __forceinline__ float wredsum(float v){
#pragma unroll
  for (int s = 32; s > 0; s >>= 1) v += __shfl_xor(v, s);
  return v;
}
__device__ __forceinline__ uint16_t f2b(float f){
  __hip_bfloat16 h = __float2bfloat16(f);
  return *(uint16_t*)&h;
}
__device__ __forceinline__ float b2f(uint16_t u){
  union{uint32_t i; float f;} a; a.i = ((uint32_t)u)<<16; return a.f;
}

__device__ __forceinline__ float dot2p(uint32_t w, uint32_t h, float acc){
#if __has_builtin(__builtin_amdgcn_fdot2)
  return __builtin_amdgcn_fdot2(__builtin_bit_cast(hf2, w), __builtin_bit_cast(hf2, h), acc, false);
#else
  hf2 wv = __builtin_bit_cast(hf2, w), hv = __builtin_bit_cast(hf2, h);
  return acc + (float)wv.x*(float)hv.x + (float)wv.y*(float)hv.y;
#endif
}

// ---- prep: wih16[n][k] = bf16(w_ih_dir[g][k]) (n = dir*1024+g); bias[n] = b_ih+b_hh ----
__global__ void prep2(const float* __restrict__ wihf, const float* __restrict__ wihb,
                      const float* __restrict__ bif, const float* __restrict__ bhf,
                      const float* __restrict__ bib, const float* __restrict__ bhb,
                      uint16_t* __restrict__ wih16, float* __restrict__ bias){
  int idx = blockIdx.x*256 + threadIdx.x;       // < 2048*256
  int n = idx >> 8;
  int k = idx & 255;
  const float* w = (n < 1024) ? wihf : wihb;
  int g = n & 1023;
  wih16[idx] = f2b(w[g*256 + k]);
  if (idx < 2048) {
    bias[idx] = (idx < 1024) ? (bif[idx] + bhf[idx]) : (bib[idx-1024] + bhb[idx-1024]);
  }
}

// ---- prep: pack w_hh for the 512-thread (j2, ks) assignment ----
// tid = j2*4+ks. Thread owns 8 cols: units {2j2, 2j2+1} x 4 gates, k-quarter ks
// (32 pairs/col). col c = g*2+u. r map: r<192: c=r>>5,p=r&31; 192..223: col6;
// 224..255: col7.
__global__ void prep_wph3(const float* __restrict__ whf, const float* __restrict__ whb,
                          uint32_t* __restrict__ wph){
  int idx = blockIdx.x*256 + threadIdx.x;       // < 2*256*512
  int dir = idx >> 17;
  int rem = idx & 131071;
  int r = rem >> 9;         // 0..255
  int tid = rem & 511;
  int j2 = tid >> 2, ks = tid & 3;
  int c, p;
  if (r < 192)      { c = r >> 5; p = r & 31; }
  else if (r < 224) { c = 6; p = r - 192; }
  else              { c = 7; p = r - 224; }
  int g = c >> 1, u = c & 1;
  int j = 2*j2 + u;
  int k = ks*64 + 2*p;
  const float* w = dir ? whb : whf;
  const float* row = w + (size_t)(g*256 + j)*256 + k;
  _Float16 lo = (_Float16)row[0];
  _Float16 hi = (_Float16)row[1];
  uint16_t l16 = __builtin_bit_cast(uint16_t, lo);
  uint16_t h16 = __builtin_bit_cast(uint16_t, hi);
  wph[idx] = (uint32_t)l16 | ((uint32_t)h16 << 16);
}

// ---- input projection via MFMA: xg[m][u*4+g] = emb[tok(m)] . w_ih[n] + bias[n] ----
__global__ __launch_bounds__(256) void inproj_mfma(const int* __restrict__ inp,
    const float* __restrict__ emb, const uint16_t* __restrict__ wih16,
    const float* __restrict__ bias, uint16_t* __restrict__ xgf,
    uint16_t* __restrict__ xgb){
  __shared__ uint16_t As[64][72];    // A[m][k] bf16, +8 pad
  __shared__ uint16_t Bs[128][72];   // B^T[c][k] = w_ih[n0+c][k] bf16, +8 pad
  __shared__ int toks[64];
  int bm = blockIdx.x, bn = blockIdx.y;
  int tid = threadIdx.x;
  if (tid < 64) {
    int m = bm*64 + tid;                       // b = m&63, t = m>>6
    toks[tid] = inp[(m & 63)*S_LEN + (m >> 6)];
  }
  __syncthreads();
  int w = tid >> 6, l = tid & 63;
  int lr = l & 15, lg = l >> 4;
  f32x4 acc[8];
#pragma unroll
  for (int cf = 0; cf < 8; ++cf) acc[cf] = (f32x4){0.f,0.f,0.f,0.f};

  int am = tid >> 2, aq = tid & 3;             // A staging: row am, 16 k each
  int bc = tid >> 1, bh = tid & 1;             // B staging: row bc, 32 k each

  for (int k0 = 0; k0 < 256; k0 += 64) {
    {
      const float* asrc = emb + (size_t)toks[am]*256 + k0 + aq*16;
      float4 v0 = *(const float4*)(asrc+0);
      float4 v1 = *(const float4*)(asrc+4);
      float4 v2 = *(const float4*)(asrc+8);
      float4 v3 = *(const float4*)(asrc+12);
      uint16_t t16[16];
      t16[0]=f2b(v0.x); t16[1]=f2b(v0.y); t16[2]=f2b(v0.z); t16[3]=f2b(v0.w);
      t16[4]=f2b(v1.x); t16[5]=f2b(v1.y); t16[6]=f2b(v1.z); t16[7]=f2b(v1.w);
      t16[8]=f2b(v2.x); t16[9]=f2b(v2.y); t16[10]=f2b(v2.z); t16[11]=f2b(v2.w);
      t16[12]=f2b(v3.x); t16[13]=f2b(v3.y); t16[14]=f2b(v3.z); t16[15]=f2b(v3.w);
      *(uint4*)&As[am][aq*16]     = *(uint4*)&t16[0];
      *(uint4*)&As[am][aq*16 + 8] = *(uint4*)&t16[8];
    }
    {
      const uint16_t* bsrc = wih16 + (size_t)(bn*128 + bc)*256 + k0 + bh*32;
      uint4 b0 = *(const uint4*)(bsrc+0);
      uint4 b1 = *(const uint4*)(bsrc+8);
      uint4 b2 = *(const uint4*)(bsrc+16);
      uint4 b3 = *(const uint4*)(bsrc+24);
      *(uint4*)&Bs[bc][bh*32+0]  = b0;
      *(uint4*)&Bs[bc][bh*32+8]  = b1;
      *(uint4*)&Bs[bc][bh*32+16] = b2;
      *(uint4*)&Bs[bc][bh*32+24] = b3;
    }
    __syncthreads();
#pragma unroll
    for (int ks = 0; ks < 2; ++ks) {
      int koff = ks*32 + lg*8;
      bf16x8 a = *(const bf16x8*)&As[16*w + lr][koff];
#pragma unroll
      for (int cf = 0; cf < 8; ++cf) {
        bf16x8 b = *(const bf16x8*)&Bs[cf*16 + lr][koff];
        acc[cf] = __builtin_amdgcn_mfma_f32_16x16x32_bf16(a, b, acc[cf], 0, 0, 0);
      }
    }
    __syncthreads();
  }
  int n0 = bn*128;
  bool back = (n0 >= 1024);
  uint16_t* dst = back ? xgb : xgf;
  int nb0 = back ? (n0 - 1024) : n0;
#pragma unroll
  for (int cf = 0; cf < 8; ++cf) {
    int nc = cf*16 + lr;
    int nd = nb0 + nc;                 // within-dir column
    int gj = (nd & 255)*4 + (nd >> 8); // unit-major, gate-minor position
    float bv = bias[n0 + nc];
#pragma unroll
    for (int r = 0; r < 4; ++r) {
      int m = bm*64 + 16*w + lg*4 + r;
      dst[(size_t)m*1024 + gj] = f2b(acc[cf][r] + bv);
    }
  }
}

// ---- recurrence: TWO same-dir chains per wg (weights shared!), 64 wgs, 512 threads ----
// tid = j2*4+ks; thread owns 8 gate-cols (units 2j2,2j2+1 x 4 gates), k-quarter ks,
// and computes those cols for BOTH chains (batch bA = wg&31, bB = bA+32).
// Weights: 192 pairs reg-resident (budget 256 @ 2 waves/SIMD), 64 pairs in LDS,
// each weight consumed twice per step (A then B) -> traffic/chain halved, and the
// two independent chains fill each other's latency stalls.
__global__ __launch_bounds__(512, 2)
void lstm7(const uint32_t* __restrict__ wph,
    const uint16_t* __restrict__ xgf, const uint16_t* __restrict__ xgb,
    __hip_bfloat16* __restrict__ hout){
  int wg = blockIdx.x;          // 64 wgs = dir*32 + bpair
  int dir = wg >> 5;
  int bA = wg & 31;
  int bB = bA + 32;
  int tid = threadIdx.x;
  int j2 = tid >> 2, ks = tid & 3;
  __shared__ uint4 wl[NWL][512];                   // 128 KB
  __shared__ __align__(16) _Float16 hsA[2][4][72]; // skewed windows, dbuf
  __shared__ __align__(16) _Float16 hsB[2][4][72];

  const uint32_t* wp = wph + (size_t)dir*131072 + tid;
  uint32_t wreg[NREG];
#pragma unroll
  for (int r = 0; r < NREG; ++r) wreg[r] = wp[r*512];
#pragma unroll
  for (int q = 0; q < NWL; ++q) {
    uint4 v;
    v.x = wp[(NREG + 4*q + 0)*512];
    v.y = wp[(NREG + 4*q + 1)*512];
    v.z = wp[(NREG + 4*q + 2)*512];
    v.w = wp[(NREG + 4*q + 3)*512];
    wl[q][tid] = v;
  }
#pragma unroll
  for (int r = 0; r < NREG; ++r) asm volatile("" : "+v"(wreg[r]));
  asm volatile("" ::: "memory");
  if (tid < 288) {
    ((_Float16*)hsA)[tid] = (_Float16)0.f;   // hsA[0][*][*]
    ((_Float16*)hsB)[tid] = (_Float16)0.f;
  }
  float cA0 = 0.f, cA1 = 0.f, cB0 = 0.f, cB1 = 0.f;
  const uint16_t* xgA = (dir ? xgb : xgf) + (size_t)bA*1024 + j2*8;
  const uint16_t* xgB = (dir ? xgb : xgf) + (size_t)bB*1024 + j2*8;
  __syncthreads();

  for (int t = 0; t < S_LEN; ++t) {
    int ts = dir ? (S_LEN-1-t) : t;
    int cur = t & 1;
    uint4 xqA = *(const uint4*)(xgA + (size_t)ts*65536);  // consumed after dots
    uint4 xqB = *(const uint4*)(xgB + (size_t)ts*65536);
    float zA[8] = {0.f,0.f,0.f,0.f,0.f,0.f,0.f,0.f};
    float zB[8] = {0.f,0.f,0.f,0.f,0.f,0.f,0.f,0.f};
    const uint4* hpA = (const uint4*)&hsA[cur][ks][0];
    const uint4* hpB = (const uint4*)&hsB[cur][ks][0];
#pragma unroll
    for (int q = 0; q < 8; ++q) {
      uint4 hqa = hpA[q];
      uint4 hqb = hpB[q];
      uint4 w6 = wl[q][tid];
      uint4 w7 = wl[8+q][tid];
#pragma unroll
      for (int cc = 0; cc < 6; ++cc) {
        uint32_t w0 = wreg[cc*32 + 4*q + 0];
        uint32_t w1 = wreg[cc*32 + 4*q + 1];
        uint32_t w2 = wreg[cc*32 + 4*q + 2];
        uint32_t w3 = wreg[cc*32 + 4*q + 3];
        zA[cc] = dot2p(w0, hqa.x, zA[cc]);
        zB[cc] = dot2p(w0, hqb.x, zB[cc]);
        zA[cc] = dot2p(w1, hqa.y, zA[cc]);
        zB[cc] = dot2p(w1, hqb.y, zB[cc]);
        zA[cc] = dot2p(w2, hqa.z, zA[cc]);
        zB[cc] = dot2p(w2, hqb.z, zB[cc]);
        zA[cc] = dot2p(w3, hqa.w, zA[cc]);
        zB[cc] = dot2p(w3, hqb.w, zB[cc]);
      }
      zA[6] = dot2p(w6.x, hqa.x, zA[6]);  zB[6] = dot2p(w6.x, hqb.x, zB[6]);
      zA[6] = dot2p(w6.y, hqa.y, zA[6]);  zB[6] = dot2p(w6.y, hqb.y, zB[6]);
      zA[6] = dot2p(w6.z, hqa.z, zA[6]);  zB[6] = dot2p(w6.z, hqb.z, zB[6]);
      zA[6] = dot2p(w6.w, hqa.w, zA[6]);  zB[6] = dot2p(w6.w, hqb.w, zB[6]);
      zA[7] = dot2p(w7.x, hqa.x, zA[7]);  zB[7] = dot2p(w7.x, hqb.x, zB[7]);
      zA[7] = dot2p(w7.y, hqa.y, zA[7]);  zB[7] = dot2p(w7.y, hqb.y, zB[7]);
      zA[7] = dot2p(w7.z, hqa.z, zA[7]);  zB[7] = dot2p(w7.z, hqb.z, zB[7]);
      zA[7] = dot2p(w7.w, hqa.w, zA[7]);  zB[7] = dot2p(w7.w, hqb.w, zB[7]);
    }
    // reduce the 4 k-quarter partials (lanes ks = 0..3 within each quad)
#pragma unroll
    for (int cc = 0; cc < 8; ++cc) { zA[cc] += __shfl_xor(zA[cc], 1); zB[cc] += __shfl_xor(zB[cc], 1); }
#pragma unroll
    for (int cc = 0; cc < 8; ++cc) { zA[cc] += __shfl_xor(zA[cc], 2); zB[cc] += __shfl_xor(zB[cc], 2); }
    // add x: col c = g*2+u -> xh[(c&1)*4 + (c>>1)]
    uint16_t xa[8], xb_[8];
    *(uint4*)xa  = xqA;
    *(uint4*)xb_ = xqB;
#pragma unroll
    for (int cc = 0; cc < 8; ++cc) {
      zA[cc] += b2f(xa[(cc & 1)*4 + (cc >> 1)]);
      zB[cc] += b2f(xb_[(cc & 1)*4 + (cc >> 1)]);
    }
    // pointwise: 2 units x 2 chains (redundant across the 4 ks lanes)
    float iA0 = sigf(zA[0]), fA0 = sigf(zA[2]), gA0 = tanh_(zA[4]), oA0 = sigf(zA[6]);
    cA0 = fA0*cA0 + iA0*gA0;
    float hA0 = oA0 * tanh_(cA0);
    float iA1 = sigf(zA[1]), fA1 = sigf(zA[3]), gA1 = tanh_(zA[5]), oA1 = sigf(zA[7]);
    cA1 = fA1*cA1 + iA1*gA1;
    float hA1 = oA1 * tanh_(cA1);
    float iB0 = sigf(zB[0]), fB0 = sigf(zB[2]), gB0 = tanh_(zB[4]), oB0 = sigf(zB[6]);
    cB0 = fB0*cB0 + iB0*gB0;
    float hB0 = oB0 * tanh_(cB0);
    float iB1 = sigf(zB[1]), fB1 = sigf(zB[3]), gB1 = tanh_(zB[5]), oB1 = sigf(zB[7]);
    cB1 = fB1*cB1 + iB1*gB1;
    float hB1 = oB1 * tanh_(cB1);
    if (ks == 0) {
      hf2 pa; pa.x = (_Float16)hA0; pa.y = (_Float16)hA1;
      hf2 pb; pb.x = (_Float16)hB0; pb.y = (_Float16)hB1;
      int win = j2 >> 5, wo = (2*j2) & 63;
      *(uint32_t*)&hsA[cur^1][win][wo] = __builtin_bit_cast(uint32_t, pa);
      *(uint32_t*)&hsB[cur^1][win][wo] = __builtin_bit_cast(uint32_t, pb);
      uint32_t ha = (uint32_t)f2b(hA0) | ((uint32_t)f2b(hA1) << 16);
      uint32_t hb = (uint32_t)f2b(hB0) | ((uint32_t)f2b(hB1) << 16);
      *(uint32_t*)&hout[((size_t)ts*BATCH + bA)*512 + dir*256 + 2*j2] = ha;
      *(uint32_t*)&hout[((size_t)ts*BATCH + bB)*512 + dir*256 + 2*j2] = hb;
    }
    __syncthreads();
  }
}

// ---- output projection: emissions[t*64+b][j] = h . w_out[j+1] + b_out[j+1] ----
__global__ __launch_bounds__(256) void outproj(const __hip_bfloat16* __restrict__ hb,
    const float* __restrict__ w_out, const float* __restrict__ b_out,
    float* __restrict__ em){
  __shared__ float wsm[NT*512];
  __shared__ float bsm[NT];
  int tid = threadIdx.x;
  for (int i = tid; i < NT*512; i += 256) wsm[i] = w_out[512 + i];  // rows 1..9
  if (tid < NT) bsm[tid] = b_out[1 + tid];
  __syncthreads();
  int wave = tid >> 6, l = tid & 63;
  int m = blockIdx.x*4 + wave;
  const __hip_bfloat16* hp = hb + (size_t)m*512;
  float hv[8];
#pragma unroll
  for (int q = 0; q < 8; ++q) hv[q] = __bfloat162float(hp[l + 64*q]);
  for (int jj = 0; jj < NT; ++jj) {
    float p = 0.f;
#pragma unroll
    for (int q = 0; q < 8; ++q) p += hv[q]*wsm[jj*512 + 64*q + l];
    p = wredsum(p);
    if (l == 0) em[(size_t)m*NT + jj] = p + bsm[jj];
  }
}

// ---- CRF: one wave per batch item; lanes 0..8 hold the 9-state score ----
__global__ __launch_bounds__(64) void crf(const int* __restrict__ tags,
    const float* __restrict__ em, const float* __restrict__ start_t,
    const float* __restrict__ end_t, const float* __restrict__ trans,
    float* __restrict__ part){
  int b = blockIdx.x;
  int l = threadIdx.x;
  float np = 0.f;
  for (int t = l; t < S_LEN; t += 64) {
    int tg = tags[b*S_LEN + t] - 1;
    float e = em[(size_t)(t*BATCH + b)*NT + tg];
    float tr = (t == 0) ? start_t[tg] : trans[(tags[b*S_LEN + t - 1] - 1)*NT + tg];
    np += e + tr;
  }
  float num = wredsum(np);
  num += end_t[tags[b*S_LEN + S_LEN-1] - 1];
  int j = (l < NT) ? l : 0;
  float tj[NT];
#pragma unroll
  for (int i = 0; i < NT; ++i) tj[i] = trans[i*NT + j];
  float sc = start_t[j] + em[(size_t)b*NT + j];
  for (int t = 1; t < S_LEN; ++t) {
    float e = em[(size_t)(t*BATCH + b)*NT + j];
    float m = -1e30f;
    float vals[NT];
#pragma unroll
    for (int i = 0; i < NT; ++i) { float si = __shfl(sc, i); vals[i] = si + tj[i]; m = fmaxf(m, vals[i]); }
    float ssum = 0.f;
#pragma unroll
    for (int i = 0; i < NT; ++i) ssum += __expf(vals[i] - m);
    sc = e + m + __logf(ssum);
  }
  float vj = (l < NT) ? (sc + end_t[l]) : -1e30f;
  float mx = vj;
#pragma unroll
  for (int s2 = 32; s2 > 0; s2 >>= 1) mx = fmaxf(mx, __shfl_xor(mx, s2));
  float es = __expf(vj - mx);
  es = wredsum(es);
  if (l == 0) part[b] = num - (mx + __logf(es));
}

__global__ void finalize(const float* __restrict__ part, float* __restrict__ out){
  float v = part[threadIdx.x];
  v = wredsum(v);
  if (threadIdx.x == 0) out[0] = -(v / 64.f);
}

extern "C" void kernel_launch(void* const* d_in, const int* in_sizes, int n_in,
                              void* d_out, int out_size, void* d_ws, size_t ws_size,
                              hipStream_t stream) {
  (void)in_sizes; (void)n_in; (void)out_size; (void)ws_size;
  const int*   inputs  = (const int*)d_in[0];
  const int*   tags    = (const int*)d_in[1];
  const float* emb     = (const float*)d_in[3];
  const float* w_ih_f  = (const float*)d_in[4];
  const float* w_hh_f  = (const float*)d_in[5];
  const float* b_ih_f  = (const float*)d_in[6];
  const float* b_hh_f  = (const float*)d_in[7];
  const float* w_ih_b  = (const float*)d_in[8];
  const float* w_hh_b  = (const float*)d_in[9];
  const float* b_ih_b  = (const float*)d_in[10];
  const float* b_hh_b  = (const float*)d_in[11];
  const float* w_out   = (const float*)d_in[12];
  const float* b_out   = (const float*)d_in[13];
  const float* start_t = (const float*)d_in[14];
  const float* end_t   = (const float*)d_in[15];
  const float* trans   = (const float*)d_in[16];

  char* ws = (char*)d_ws;
  size_t off = 0;
  auto alloc = [&](size_t bytes) -> void* {
    void* p = ws + off;
    off = (off + bytes + 255) & ~(size_t)255;
    return p;
  };
  uint16_t* xgf = (uint16_t*)alloc((size_t)NTOK*1024*2);
  uint16_t* xgb = (uint16_t*)alloc((size_t)NTOK*1024*2);
  __hip_bfloat16* hbf = (__hip_bfloat16*)alloc((size_t)NTOK*512*2);
  float*    em    = (float*)alloc((size_t)NTOK*NT*4);
  uint16_t* wih16 = (uint16_t*)alloc((size_t)2048*256*2);
  float*    bias  = (float*)alloc((size_t)2048*4);
  uint32_t* wph   = (uint32_t*)alloc((size_t)2*256*512*4);
  float*    part  = (float*)alloc((size_t)64*4);

  prep2<<<2048, 256, 0, stream>>>(w_ih_f, w_ih_b, b_ih_f, b_hh_f, b_ih_b, b_hh_b, wih16, bias);
  prep_wph3<<<1024, 256, 0, stream>>>(w_hh_f, w_hh_b, wph);
  inproj_mfma<<<dim3(256, 16), 256, 0, stream>>>(inputs, emb, wih16, bias, xgf, xgb);
  lstm7<<<64, 512, 0, stream>>>(wph, xgf, xgb, hbf);
  outproj<<<4096, 256, 0, stream>>>(hbf, w_out, b_out, em);
  crf<<<64, 64, 0, stream>>>(tags, em, start_t, end_t, trans, part);
  finalize<<<1, 64, 0, stream>>>(part, (float*)d_out);
}

// Round 10
// 787.912 us; speedup vs baseline: 40.6478x; 1.4937x over previous
//
#include <hip/hip_runtime.h>
#include <hip/hip_bf16.h>
#include <stdint.h>

#define S_LEN 256
#define BATCH 64
#define HD 256
#define NT 9
#define NTOK (S_LEN*BATCH)   // 16384

typedef _Float16 hf2 __attribute__((ext_vector_type(2)));
typedef short bf16x8 __attribute__((ext_vector_type(8)));
typedef float f32x4 __attribute__((ext_vector_type(4)));

__device__ __forceinline__ float sigf(float x){ return 1.f/(1.f+__expf(-x)); }
__device__ __forceinline__ float tanh_(float x){ return 1.f - 2.f/(__expf(2.f*x)+1.f); }
__device__ __forceinline__ float wredsum(float v){
#pragma unroll
  for (int s = 32; s > 0; s >>= 1) v += __shfl_xor(v, s);
  return v;
}
__device__ __forceinline__ uint16_t f2b(float f){
  __hip_bfloat16 h = __float2bfloat16(f);
  return *(uint16_t*)&h;
}
__device__ __forceinline__ float b2f(uint16_t u){
  union{uint32_t i; float f;} a; a.i = ((uint32_t)u)<<16; return a.f;
}

__device__ __forceinline__ int sdot4(uint32_t a, uint32_t b, int c){
#if __has_builtin(__builtin_amdgcn_sdot4)
  return __builtin_amdgcn_sdot4((int)a, (int)b, c, false);
#else
  int r = c;
#pragma unroll
  for (int e = 0; e < 4; ++e) {
    int av = (int)(signed char)((a >> (8*e)) & 0xff);
    int bv = (int)(signed char)((b >> (8*e)) & 0xff);
    r += av * bv;
  }
  return r;
#endif
}

// ---- prep: wih16[n][k] = bf16(w_ih_dir[g][k]) (n = dir*1024+g); bias[n] = b_ih+b_hh ----
__global__ void prep2(const float* __restrict__ wihf, const float* __restrict__ wihb,
                      const float* __restrict__ bif, const float* __restrict__ bhf,
                      const float* __restrict__ bib, const float* __restrict__ bhb,
                      uint16_t* __restrict__ wih16, float* __restrict__ bias){
  int idx = blockIdx.x*256 + threadIdx.x;       // < 2048*256
  int n = idx >> 8;
  int k = idx & 255;
  const float* w = (n < 1024) ? wihf : wihb;
  int g = n & 1023;
  wih16[idx] = f2b(w[g*256 + k]);
  if (idx < 2048) {
    bias[idx] = (idx < 1024) ? (bif[idx] + bhf[idx]) : (bib[idx-1024] + bhb[idx-1024]);
  }
}

// ---- prep: per-gate-column symmetric i8 scale: mult[dir*1024+c] = amax_c/(127*127) ----
__global__ void prep_scale(const float* __restrict__ whf, const float* __restrict__ whb,
                           float* __restrict__ mult){
  int idx = blockIdx.x*256 + threadIdx.x;   // < 2048
  int dir = idx >> 10, c = idx & 1023;
  const float* w = (dir ? whb : whf) + (size_t)c*256;
  float amax = 0.f;
  for (int k = 0; k < 256; ++k) amax = fmaxf(amax, fabsf(w[k]));
  mult[idx] = amax / 16129.f;   // = (amax/127) * (1/127)
}

// ---- prep: pack w_hh to i8x4 for lstm8's (j2, ks) layout ----
// tid = j2*8+ks. Thread owns 8 cols cc = g*2+u (units 2j2,2j2+1 x 4 gates),
// k-window [32ks, +32) = 8 dwords. wpk8[(dir*64 + cc*8 + p)*1024 + tid]:
// byte e = round(w[g*256+u][ks*32+4p+e] / sw_col), sw_col = mult*127.
__global__ void prep_pack8(const float* __restrict__ whf, const float* __restrict__ whb,
                           const float* __restrict__ mult, uint32_t* __restrict__ wpk8){
  int idx = blockIdx.x*256 + threadIdx.x;   // < 131072
  int dir = idx >> 16;
  int rem = idx & 65535;
  int r = rem >> 10;        // 0..63 = cc*8 + p
  int tid = rem & 1023;
  int cc = r >> 3, p = r & 7;
  int g = cc >> 1;
  int j2 = tid >> 3, ks = tid & 7;
  int u = 2*j2 + (cc & 1);
  int col = g*256 + u;
  const float* w = (dir ? whb : whf) + (size_t)col*256 + ks*32 + p*4;
  float sw = mult[dir*1024 + col] * 127.f;
  float inv = (sw > 0.f) ? (1.f/sw) : 0.f;
  uint32_t pk = 0;
#pragma unroll
  for (int e = 0; e < 4; ++e) {
    float q = rintf(w[e] * inv);
    q = fminf(127.f, fmaxf(-127.f, q));
    int qi = (int)q;
    pk |= ((uint32_t)(qi & 0xff)) << (8*e);
  }
  wpk8[idx] = pk;
}

// ---- input projection via MFMA: xg[m][u*4+g] = emb[tok(m)] . w_ih[n] + bias[n] ----
__global__ __launch_bounds__(256) void inproj_mfma(const int* __restrict__ inp,
    const float* __restrict__ emb, const uint16_t* __restrict__ wih16,
    const float* __restrict__ bias, uint16_t* __restrict__ xgf,
    uint16_t* __restrict__ xgb){
  __shared__ uint16_t As[64][72];    // A[m][k] bf16, +8 pad
  __shared__ uint16_t Bs[128][72];   // B^T[c][k] = w_ih[n0+c][k] bf16, +8 pad
  __shared__ int toks[64];
  int bm = blockIdx.x, bn = blockIdx.y;
  int tid = threadIdx.x;
  if (tid < 64) {
    int m = bm*64 + tid;                       // b = m&63, t = m>>6
    toks[tid] = inp[(m & 63)*S_LEN + (m >> 6)];
  }
  __syncthreads();
  int w = tid >> 6, l = tid & 63;
  int lr = l & 15, lg = l >> 4;
  f32x4 acc[8];
#pragma unroll
  for (int cf = 0; cf < 8; ++cf) acc[cf] = (f32x4){0.f,0.f,0.f,0.f};

  int am = tid >> 2, aq = tid & 3;             // A staging: row am, 16 k each
  int bc = tid >> 1, bh = tid & 1;             // B staging: row bc, 32 k each

  for (int k0 = 0; k0 < 256; k0 += 64) {
    {
      const float* asrc = emb + (size_t)toks[am]*256 + k0 + aq*16;
      float4 v0 = *(const float4*)(asrc+0);
      float4 v1 = *(const float4*)(asrc+4);
      float4 v2 = *(const float4*)(asrc+8);
      float4 v3 = *(const float4*)(asrc+12);
      uint16_t t16[16];
      t16[0]=f2b(v0.x); t16[1]=f2b(v0.y); t16[2]=f2b(v0.z); t16[3]=f2b(v0.w);
      t16[4]=f2b(v1.x); t16[5]=f2b(v1.y); t16[6]=f2b(v1.z); t16[7]=f2b(v1.w);
      t16[8]=f2b(v2.x); t16[9]=f2b(v2.y); t16[10]=f2b(v2.z); t16[11]=f2b(v2.w);
      t16[12]=f2b(v3.x); t16[13]=f2b(v3.y); t16[14]=f2b(v3.z); t16[15]=f2b(v3.w);
      *(uint4*)&As[am][aq*16]     = *(uint4*)&t16[0];
      *(uint4*)&As[am][aq*16 + 8] = *(uint4*)&t16[8];
    }
    {
      const uint16_t* bsrc = wih16 + (size_t)(bn*128 + bc)*256 + k0 + bh*32;
      uint4 b0 = *(const uint4*)(bsrc+0);
      uint4 b1 = *(const uint4*)(bsrc+8);
      uint4 b2 = *(const uint4*)(bsrc+16);
      uint4 b3 = *(const uint4*)(bsrc+24);
      *(uint4*)&Bs[bc][bh*32+0]  = b0;
      *(uint4*)&Bs[bc][bh*32+8]  = b1;
      *(uint4*)&Bs[bc][bh*32+16] = b2;
      *(uint4*)&Bs[bc][bh*32+24] = b3;
    }
    __syncthreads();
#pragma unroll
    for (int ks = 0; ks < 2; ++ks) {
      int koff = ks*32 + lg*8;
      bf16x8 a = *(const bf16x8*)&As[16*w + lr][koff];
#pragma unroll
      for (int cf = 0; cf < 8; ++cf) {
        bf16x8 b = *(const bf16x8*)&Bs[cf*16 + lr][koff];
        acc[cf] = __builtin_amdgcn_mfma_f32_16x16x32_bf16(a, b, acc[cf], 0, 0, 0);
      }
    }
    __syncthreads();
  }
  int n0 = bn*128;
  bool back = (n0 >= 1024);
  uint16_t* dst = back ? xgb : xgf;
  int nb0 = back ? (n0 - 1024) : n0;
#pragma unroll
  for (int cf = 0; cf < 8; ++cf) {
    int nc = cf*16 + lr;
    int nd = nb0 + nc;                 // within-dir column
    int gj = (nd & 255)*4 + (nd >> 8); // unit-major, gate-minor position
    float bv = bias[n0 + nc];
#pragma unroll
    for (int r = 0; r < 4; ++r) {
      int m = bm*64 + 16*w + lg*4 + r;
      dst[(size_t)m*1024 + gj] = f2b(acc[cf][r] + bv);
    }
  }
}

// ---- recurrence: one wg per (dir, batch); 1024 threads = (j2, ks); int8 dot4 ----
// Thread: units {2j2, 2j2+1} x 4 gates over k-window [32ks, +32) = 64 i8x4 dwords,
// ALL arch-VGPR-resident (~115 regs < 128 budget at 4 waves/SIMD). h quantized to
// i8 (x127) in LDS (256 B dbuf). 64 sdot4 + 3-round octet shfl (exact i32 reduce),
// z = mult_col * dot + x. 1 barrier/step, 16 waves/wg = 4/SIMD latency hiding.
__global__ __launch_bounds__(1024, 4)
void lstm8(const uint32_t* __restrict__ wpk8, const float* __restrict__ mult,
    const uint16_t* __restrict__ xgf, const uint16_t* __restrict__ xgb,
    __hip_bfloat16* __restrict__ hout){
  int dir = blockIdx.x >> 6;
  int b = blockIdx.x & 63;
  int tid = threadIdx.x;
  int j2 = tid >> 3, ks = tid & 7;
  __shared__ __align__(16) uint32_t hs8[2][64];   // h as i8*127, double-buffered

  const uint32_t* wp = wpk8 + (size_t)dir*65536 + tid;
  uint32_t wreg[64];
#pragma unroll
  for (int r = 0; r < 64; ++r) wreg[r] = wp[r*1024];
#pragma unroll
  for (int r = 0; r < 64; ++r) asm volatile("" : "+v"(wreg[r]));
  asm volatile("" ::: "memory");

  float mult8[8];
#pragma unroll
  for (int cc = 0; cc < 8; ++cc)
    mult8[cc] = mult[dir*1024 + (cc >> 1)*256 + 2*j2 + (cc & 1)];

  if (tid < 64) hs8[0][tid] = 0u;
  float c0 = 0.f, c1 = 0.f;
  const uint16_t* xgp = (dir ? xgb : xgf) + (size_t)b*1024 + j2*8;
  __syncthreads();

  int ts0 = dir ? (S_LEN-1) : 0;
  uint4 xq = *(const uint4*)(xgp + (size_t)ts0*65536);
  for (int t = 0; t < S_LEN; ++t) {
    int ts = dir ? (S_LEN-1-t) : t;
    int cur = t & 1;
    uint4 xnext = xq;
    if (t + 1 < S_LEN) {
      int tn = dir ? (S_LEN-2-t) : (t+1);
      xnext = *(const uint4*)(xgp + (size_t)tn*65536);
    }
    // h window: 8 dwords (32 i8) at dword ks*8
    const uint4* hp = (const uint4*)&hs8[cur][ks*8];
    uint4 hA = hp[0];
    uint4 hB = hp[1];
    int zc[8] = {0,0,0,0,0,0,0,0};
#pragma unroll
    for (int cc = 0; cc < 8; ++cc) {
      zc[cc] = sdot4(wreg[cc*8+0], hA.x, zc[cc]);
      zc[cc] = sdot4(wreg[cc*8+1], hA.y, zc[cc]);
      zc[cc] = sdot4(wreg[cc*8+2], hA.z, zc[cc]);
      zc[cc] = sdot4(wreg[cc*8+3], hA.w, zc[cc]);
      zc[cc] = sdot4(wreg[cc*8+4], hB.x, zc[cc]);
      zc[cc] = sdot4(wreg[cc*8+5], hB.y, zc[cc]);
      zc[cc] = sdot4(wreg[cc*8+6], hB.z, zc[cc]);
      zc[cc] = sdot4(wreg[cc*8+7], hB.w, zc[cc]);
    }
    // exact i32 reduce over the 8 k-windows (lanes ks = 0..7 in each octet)
#pragma unroll
    for (int cc = 0; cc < 8; ++cc) zc[cc] += __shfl_xor(zc[cc], 1);
#pragma unroll
    for (int cc = 0; cc < 8; ++cc) zc[cc] += __shfl_xor(zc[cc], 2);
#pragma unroll
    for (int cc = 0; cc < 8; ++cc) zc[cc] += __shfl_xor(zc[cc], 4);
    // z = mult_col * dot + x  (x layout [u][g]: col c=g*2+u -> xh[(c&1)*4+(c>>1)])
    uint16_t xh[8];
    *(uint4*)xh = xq;
    float zf[8];
#pragma unroll
    for (int cc = 0; cc < 8; ++cc)
      zf[cc] = (float)zc[cc] * mult8[cc] + b2f(xh[(cc & 1)*4 + (cc >> 1)]);
    // pointwise, both units (redundant across the 8 ks lanes)
    float ig0 = sigf(zf[0]), fg0 = sigf(zf[2]), gg0 = tanh_(zf[4]), og0 = sigf(zf[6]);
    c0 = fg0*c0 + ig0*gg0;
    float h0 = og0 * tanh_(c0);
    float ig1 = sigf(zf[1]), fg1 = sigf(zf[3]), gg1 = tanh_(zf[5]), og1 = sigf(zf[7]);
    c1 = fg1*c1 + ig1*gg1;
    float h1 = og1 * tanh_(c1);
    if (ks == 0) {
      int q0 = (int)rintf(h0 * 127.f);
      int q1 = (int)rintf(h1 * 127.f);
      uint16_t hq = (uint16_t)((q0 & 0xff) | ((q1 & 0xff) << 8));
      ((uint16_t*)&hs8[cur^1][0])[j2] = hq;
      uint32_t hb = (uint32_t)f2b(h0) | ((uint32_t)f2b(h1) << 16);
      *(uint32_t*)&hout[((size_t)ts*BATCH + b)*512 + dir*256 + 2*j2] = hb;
    }
    xq = xnext;
    __syncthreads();
  }
}

// ---- output projection: emissions[t*64+b][j] = h . w_out[j+1] + b_out[j+1] ----
__global__ __launch_bounds__(256) void outproj(const __hip_bfloat16* __restrict__ hb,
    const float* __restrict__ w_out, const float* __restrict__ b_out,
    float* __restrict__ em){
  __shared__ float wsm[NT*512];
  __shared__ float bsm[NT];
  int tid = threadIdx.x;
  for (int i = tid; i < NT*512; i += 256) wsm[i] = w_out[512 + i];  // rows 1..9
  if (tid < NT) bsm[tid] = b_out[1 + tid];
  __syncthreads();
  int wave = tid >> 6, l = tid & 63;
  int m = blockIdx.x*4 + wave;
  const __hip_bfloat16* hp = hb + (size_t)m*512;
  float hv[8];
#pragma unroll
  for (int q = 0; q < 8; ++q) hv[q] = __bfloat162float(hp[l + 64*q]);
  for (int jj = 0; jj < NT; ++jj) {
    float p = 0.f;
#pragma unroll
    for (int q = 0; q < 8; ++q) p += hv[q]*wsm[jj*512 + 64*q + l];
    p = wredsum(p);
    if (l == 0) em[(size_t)m*NT + jj] = p + bsm[jj];
  }
}

// ---- CRF: one wave per batch item; lanes 0..8 hold the 9-state score ----
__global__ __launch_bounds__(64) void crf(const int* __restrict__ tags,
    const float* __restrict__ em, const float* __restrict__ start_t,
    const float* __restrict__ end_t, const float* __restrict__ trans,
    float* __restrict__ part){
  int b = blockIdx.x;
  int l = threadIdx.x;
  float np = 0.f;
  for (int t = l; t < S_LEN; t += 64) {
    int tg = tags[b*S_LEN + t] - 1;
    float e = em[(size_t)(t*BATCH + b)*NT + tg];
    float tr = (t == 0) ? start_t[tg] : trans[(tags[b*S_LEN + t - 1] - 1)*NT + tg];
    np += e + tr;
  }
  float num = wredsum(np);
  num += end_t[tags[b*S_LEN + S_LEN-1] - 1];
  int j = (l < NT) ? l : 0;
  float tj[NT];
#pragma unroll
  for (int i = 0; i < NT; ++i) tj[i] = trans[i*NT + j];
  float sc = start_t[j] + em[(size_t)b*NT + j];
  for (int t = 1; t < S_LEN; ++t) {
    float e = em[(size_t)(t*BATCH + b)*NT + j];
    float m = -1e30f;
    float vals[NT];
#pragma unroll
    for (int i = 0; i < NT; ++i) { float si = __shfl(sc, i); vals[i] = si + tj[i]; m = fmaxf(m, vals[i]); }
    float ssum = 0.f;
#pragma unroll
    for (int i = 0; i < NT; ++i) ssum += __expf(vals[i] - m);
    sc = e + m + __logf(ssum);
  }
  float vj = (l < NT) ? (sc + end_t[l]) : -1e30f;
  float mx = vj;
#pragma unroll
  for (int s2 = 32; s2 > 0; s2 >>= 1) mx = fmaxf(mx, __shfl_xor(mx, s2));
  float es = __expf(vj - mx);
  es = wredsum(es);
  if (l == 0) part[b] = num - (mx + __logf(es));
}

__global__ void finalize(const float* __restrict__ part, float* __restrict__ out){
  float v = part[threadIdx.x];
  v = wredsum(v);
  if (threadIdx.x == 0) out[0] = -(v / 64.f);
}

extern "C" void kernel_launch(void* const* d_in, const int* in_sizes, int n_in,
                              void* d_out, int out_size, void* d_ws, size_t ws_size,
                              hipStream_t stream) {
  (void)in_sizes; (void)n_in; (void)out_size; (void)ws_size;
  const int*   inputs  = (const int*)d_in[0];
  const int*   tags    = (const int*)d_in[1];
  const float* emb     = (const float*)d_in[3];
  const float* w_ih_f  = (const float*)d_in[4];
  const float* w_hh_f  = (const float*)d_in[5];
  const float* b_ih_f  = (const float*)d_in[6];
  const float* b_hh_f  = (const float*)d_in[7];
  const float* w_ih_b  = (const float*)d_in[8];
  const float* w_hh_b  = (const float*)d_in[9];
  const float* b_ih_b  = (const float*)d_in[10];
  const float* b_hh_b  = (const float*)d_in[11];
  const float* w_out   = (const float*)d_in[12];
  const float* b_out   = (const float*)d_in[13];
  const float* start_t = (const float*)d_in[14];
  const float* end_t   = (const float*)d_in[15];
  const float* trans   = (const float*)d_in[16];

  char* ws = (char*)d_ws;
  size_t off = 0;
  auto alloc = [&](size_t bytes) -> void* {
    void* p = ws + off;
    off = (off + bytes + 255) & ~(size_t)255;
    return p;
  };
  uint16_t* xgf = (uint16_t*)alloc((size_t)NTOK*1024*2);
  uint16_t* xgb = (uint16_t*)alloc((size_t)NTOK*1024*2);
  __hip_bfloat16* hbf = (__hip_bfloat16*)alloc((size_t)NTOK*512*2);
  float*    em    = (float*)alloc((size_t)NTOK*NT*4);
  uint16_t* wih16 = (uint16_t*)alloc((size_t)2048*256*2);
  float*    bias  = (float*)alloc((size_t)2048*4);
  float*    mult  = (float*)alloc((size_t)2048*4);
  uint32_t* wpk8  = (uint32_t*)alloc((size_t)2*64*1024*4);
  float*    part  = (float*)alloc((size_t)64*4);

  prep2<<<2048, 256, 0, stream>>>(w_ih_f, w_ih_b, b_ih_f, b_hh_f, b_ih_b, b_hh_b, wih16, bias);
  prep_scale<<<8, 256, 0, stream>>>(w_hh_f, w_hh_b, mult);
  prep_pack8<<<512, 256, 0, stream>>>(w_hh_f, w_hh_b, mult, wpk8);
  inproj_mfma<<<dim3(256, 16), 256, 0, stream>>>(inputs, emb, wih16, bias, xgf, xgb);
  lstm8<<<128, 1024, 0, stream>>>(wpk8, mult, xgf, xgb, hbf);
  outproj<<<4096, 256, 0, stream>>>(hbf, w_out, b_out, em);
  crf<<<64, 64, 0, stream>>>(tags, em, start_t, end_t, trans, part);
  finalize<<<1, 64, 0, stream>>>(part, (float*)d_out);
}

// Round 11
// 571.756 us; speedup vs baseline: 56.0150x; 1.3781x over previous
//
#include <hip/hip_runtime.h>
#include <hip/hip_bf16.h>
#include <stdint.h>

#define S_LEN 256
#define BATCH 64
#define HD 256
#define NT 9
#define NTOK (S_LEN*BATCH)   // 16384

typedef _Float16 hf2 __attribute__((ext_vector_type(2)));
typedef short bf16x8 __attribute__((ext_vector_type(8)));
typedef float f32x4 __attribute__((ext_vector_type(4)));

__device__ __forceinline__ float sigf(float x){ return 1.f/(1.f+__expf(-x)); }
__device__ __forceinline__ float tanh_(float x){ return 1.f - 2.f/(__expf(2.f*x)+1.f); }
__device__ __forceinline__ float wredsum(float v){
#pragma unroll
  for (int s = 32; s > 0; s >>= 1) v += __shfl_xor(v, s);
  return v;
}
__device__ __forceinline__ uint16_t f2b(float f){
  __hip_bfloat16 h = __float2bfloat16(f);
  return *(uint16_t*)&h;
}
__device__ __forceinline__ float b2f(uint16_t u){
  union{uint32_t i; float f;} a; a.i = ((uint32_t)u)<<16; return a.f;
}

__device__ __forceinline__ int sdot4(uint32_t a, uint32_t b, int c){
#if __has_builtin(__builtin_amdgcn_sdot4)
  return __builtin_amdgcn_sdot4((int)a, (int)b, c, false);
#else
  int r = c;
#pragma unroll
  for (int e = 0; e < 4; ++e) {
    int av = (int)(signed char)((a >> (8*e)) & 0xff);
    int bv = (int)(signed char)((b >> (8*e)) & 0xff);
    r += av * bv;
  }
  return r;
#endif
}

// ---- prep: wih16[n][k] = bf16(w_ih_dir[g][k]) (n = dir*1024+g); bias[n] = b_ih+b_hh ----
__global__ void prep2(const float* __restrict__ wihf, const float* __restrict__ wihb,
                      const float* __restrict__ bif, const float* __restrict__ bhf,
                      const float* __restrict__ bib, const float* __restrict__ bhb,
                      uint16_t* __restrict__ wih16, float* __restrict__ bias){
  int idx = blockIdx.x*256 + threadIdx.x;       // < 2048*256
  int n = idx >> 8;
  int k = idx & 255;
  const float* w = (n < 1024) ? wihf : wihb;
  int g = n & 1023;
  wih16[idx] = f2b(w[g*256 + k]);
  if (idx < 2048) {
    bias[idx] = (idx < 1024) ? (bif[idx] + bhf[idx]) : (bib[idx-1024] + bhb[idx-1024]);
  }
}

// ---- prep: per-gate-column symmetric i8 scale: mult[dir*1024+c] = amax_c/(127*127) ----
__global__ void prep_scale(const float* __restrict__ whf, const float* __restrict__ whb,
                           float* __restrict__ mult){
  int idx = blockIdx.x*256 + threadIdx.x;   // < 2048
  int dir = idx >> 10, c = idx & 1023;
  const float* w = (dir ? whb : whf) + (size_t)c*256;
  float amax = 0.f;
  for (int k = 0; k < 256; ++k) amax = fmaxf(amax, fabsf(w[k]));
  mult[idx] = amax / 16129.f;   // = (amax/127) * (1/127)
}

// ---- prep: pack w_hh to i8x4 for lstm9's (j, ks) layout ----
// tid = j*4+ks. Thread owns unit j, 4 gates, k-window [64ks, +64) = 16 dwords/gate.
// wpk9[(dir*64 + g*16 + p)*1024 + tid]: byte e = q(w[g*256+j][ks*64+4p+e]).
__global__ void prep_pack9(const float* __restrict__ whf, const float* __restrict__ whb,
                           const float* __restrict__ mult, uint32_t* __restrict__ wpk9){
  int idx = blockIdx.x*256 + threadIdx.x;   // < 131072
  int dir = idx >> 16;
  int rem = idx & 65535;
  int r = rem >> 10;        // 0..63 = g*16 + p
  int tid = rem & 1023;
  int g = r >> 4, p = r & 15;
  int j = tid >> 2, ks = tid & 3;
  int col = g*256 + j;
  const float* w = (dir ? whb : whf) + (size_t)col*256 + ks*64 + p*4;
  float sw = mult[dir*1024 + col] * 127.f;
  float inv = (sw > 0.f) ? (1.f/sw) : 0.f;
  uint32_t pk = 0;
#pragma unroll
  for (int e = 0; e < 4; ++e) {
    float q = rintf(w[e] * inv);
    q = fminf(127.f, fmaxf(-127.f, q));
    int qi = (int)q;
    pk |= ((uint32_t)(qi & 0xff)) << (8*e);
  }
  wpk9[idx] = pk;
}

// ---- input projection via MFMA: xg[m][u*4+g] = emb[tok(m)] . w_ih[n] + bias[n] ----
__global__ __launch_bounds__(256) void inproj_mfma(const int* __restrict__ inp,
    const float* __restrict__ emb, const uint16_t* __restrict__ wih16,
    const float* __restrict__ bias, uint16_t* __restrict__ xgf,
    uint16_t* __restrict__ xgb){
  __shared__ uint16_t As[64][72];    // A[m][k] bf16, +8 pad
  __shared__ uint16_t Bs[128][72];   // B^T[c][k] = w_ih[n0+c][k] bf16, +8 pad
  __shared__ int toks[64];
  int bm = blockIdx.x, bn = blockIdx.y;
  int tid = threadIdx.x;
  if (tid < 64) {
    int m = bm*64 + tid;                       // b = m&63, t = m>>6
    toks[tid] = inp[(m & 63)*S_LEN + (m >> 6)];
  }
  __syncthreads();
  int w = tid >> 6, l = tid & 63;
  int lr = l & 15, lg = l >> 4;
  f32x4 acc[8];
#pragma unroll
  for (int cf = 0; cf < 8; ++cf) acc[cf] = (f32x4){0.f,0.f,0.f,0.f};

  int am = tid >> 2, aq = tid & 3;             // A staging: row am, 16 k each
  int bc = tid >> 1, bh = tid & 1;             // B staging: row bc, 32 k each

  for (int k0 = 0; k0 < 256; k0 += 64) {
    {
      const float* asrc = emb + (size_t)toks[am]*256 + k0 + aq*16;
      float4 v0 = *(const float4*)(asrc+0);
      float4 v1 = *(const float4*)(asrc+4);
      float4 v2 = *(const float4*)(asrc+8);
      float4 v3 = *(const float4*)(asrc+12);
      uint16_t t16[16];
      t16[0]=f2b(v0.x); t16[1]=f2b(v0.y); t16[2]=f2b(v0.z); t16[3]=f2b(v0.w);
      t16[4]=f2b(v1.x); t16[5]=f2b(v1.y); t16[6]=f2b(v1.z); t16[7]=f2b(v1.w);
      t16[8]=f2b(v2.x); t16[9]=f2b(v2.y); t16[10]=f2b(v2.z); t16[11]=f2b(v2.w);
      t16[12]=f2b(v3.x); t16[13]=f2b(v3.y); t16[14]=f2b(v3.z); t16[15]=f2b(v3.w);
      *(uint4*)&As[am][aq*16]     = *(uint4*)&t16[0];
      *(uint4*)&As[am][aq*16 + 8] = *(uint4*)&t16[8];
    }
    {
      const uint16_t* bsrc = wih16 + (size_t)(bn*128 + bc)*256 + k0 + bh*32;
      uint4 b0 = *(const uint4*)(bsrc+0);
      uint4 b1 = *(const uint4*)(bsrc+8);
      uint4 b2 = *(const uint4*)(bsrc+16);
      uint4 b3 = *(const uint4*)(bsrc+24);
      *(uint4*)&Bs[bc][bh*32+0]  = b0;
      *(uint4*)&Bs[bc][bh*32+8]  = b1;
      *(uint4*)&Bs[bc][bh*32+16] = b2;
      *(uint4*)&Bs[bc][bh*32+24] = b3;
    }
    __syncthreads();
#pragma unroll
    for (int ks = 0; ks < 2; ++ks) {
      int koff = ks*32 + lg*8;
      bf16x8 a = *(const bf16x8*)&As[16*w + lr][koff];
#pragma unroll
      for (int cf = 0; cf < 8; ++cf) {
        bf16x8 b = *(const bf16x8*)&Bs[cf*16 + lr][koff];
        acc[cf] = __builtin_amdgcn_mfma_f32_16x16x32_bf16(a, b, acc[cf], 0, 0, 0);
      }
    }
    __syncthreads();
  }
  int n0 = bn*128;
  bool back = (n0 >= 1024);
  uint16_t* dst = back ? xgb : xgf;
  int nb0 = back ? (n0 - 1024) : n0;
#pragma unroll
  for (int cf = 0; cf < 8; ++cf) {
    int nc = cf*16 + lr;
    int nd = nb0 + nc;                 // within-dir column
    int gj = (nd & 255)*4 + (nd >> 8); // unit-major, gate-minor position
    float bv = bias[n0 + nc];
#pragma unroll
    for (int r = 0; r < 4; ++r) {
      int m = bm*64 + 16*w + lg*4 + r;
      dst[(size_t)m*1024 + gj] = f2b(acc[cf][r] + bv);
    }
  }
}

// ---- recurrence: one wg per (dir, batch); 1024 threads = (unit j, k-quarter ks) ----
// Thread: unit j, 4 gates, k-window [64ks,+64) = 64 i8x4 dwords, reg-resident.
// Quad reduce = xor1+xor2 only (DPP, VALU-pipe; no LDS swizzles). Raw s_barrier
// with lgkmcnt-only drain: x prefetch loads + hout stores stay in flight across
// the barrier (the __syncthreads vmcnt(0) drain was the ~2.4 us/step floor).
__global__ __launch_bounds__(1024, 4)
void lstm9(const uint32_t* __restrict__ wpk9, const float* __restrict__ mult,
    const uint16_t* __restrict__ xgf, const uint16_t* __restrict__ xgb,
    __hip_bfloat16* __restrict__ hout){
  int dir = blockIdx.x >> 6;
  int b = blockIdx.x & 63;
  int tid = threadIdx.x;
  int j = tid >> 2, ks = tid & 3;
  __shared__ __align__(16) uint32_t hs8[2][64];   // h as i8*127, double-buffered

  const uint32_t* wp = wpk9 + (size_t)dir*65536 + tid;
  uint32_t wreg[64];
#pragma unroll
  for (int r = 0; r < 64; ++r) wreg[r] = wp[r*1024];
#pragma unroll
  for (int r = 0; r < 64; ++r) asm volatile("" : "+v"(wreg[r]));
  asm volatile("" ::: "memory");

  float m4[4];
#pragma unroll
  for (int g = 0; g < 4; ++g) m4[g] = mult[dir*1024 + g*256 + j];

  if (tid < 128) hs8[tid >> 6][tid & 63] = 0u;
  float cst = 0.f;
  const uint16_t* xgp = (dir ? xgb : xgf) + (size_t)b*1024 + j*4;
  __syncthreads();

  int ts0 = dir ? (S_LEN-1) : 0;
  int ts1 = dir ? (S_LEN-2) : 1;
  uint2 xA = *(const uint2*)(xgp + (size_t)ts0*65536);   // depth-2 prefetch
  uint2 xB = *(const uint2*)(xgp + (size_t)ts1*65536);
  for (int t = 0; t < S_LEN; ++t) {
    int ts = dir ? (S_LEN-1-t) : t;
    int cur = t & 1;
    uint2 xC = xB;
    if (t + 2 < S_LEN) {
      int tn = dir ? (S_LEN-3-t) : (t+2);
      xC = *(const uint2*)(xgp + (size_t)tn*65536);
    }
    // h window: 16 dwords (64 i8) at dword ks*16 (4 b128, <=2-way alias = free)
    const uint4* hp = (const uint4*)&hs8[cur][ks*16];
    uint4 h0 = hp[0], h1 = hp[1], h2 = hp[2], h3 = hp[3];
    int zi[4] = {0,0,0,0};
#pragma unroll
    for (int g = 0; g < 4; ++g) {
      const uint32_t* wg_ = &wreg[g*16];
      zi[g] = sdot4(wg_[0],  h0.x, zi[g]);
      zi[g] = sdot4(wg_[1],  h0.y, zi[g]);
      zi[g] = sdot4(wg_[2],  h0.z, zi[g]);
      zi[g] = sdot4(wg_[3],  h0.w, zi[g]);
      zi[g] = sdot4(wg_[4],  h1.x, zi[g]);
      zi[g] = sdot4(wg_[5],  h1.y, zi[g]);
      zi[g] = sdot4(wg_[6],  h1.z, zi[g]);
      zi[g] = sdot4(wg_[7],  h1.w, zi[g]);
      zi[g] = sdot4(wg_[8],  h2.x, zi[g]);
      zi[g] = sdot4(wg_[9],  h2.y, zi[g]);
      zi[g] = sdot4(wg_[10], h2.z, zi[g]);
      zi[g] = sdot4(wg_[11], h2.w, zi[g]);
      zi[g] = sdot4(wg_[12], h3.x, zi[g]);
      zi[g] = sdot4(wg_[13], h3.y, zi[g]);
      zi[g] = sdot4(wg_[14], h3.z, zi[g]);
      zi[g] = sdot4(wg_[15], h3.w, zi[g]);
    }
    // exact i32 quad reduce (xor1, xor2 -> DPP quad_perm, VALU pipe)
#pragma unroll
    for (int g = 0; g < 4; ++g) zi[g] += __shfl_xor(zi[g], 1);
#pragma unroll
    for (int g = 0; g < 4; ++g) zi[g] += __shfl_xor(zi[g], 2);
    float zf[4];
    zf[0] = (float)zi[0]*m4[0] + b2f((uint16_t)(xA.x & 0xffff));
    zf[1] = (float)zi[1]*m4[1] + b2f((uint16_t)(xA.x >> 16));
    zf[2] = (float)zi[2]*m4[2] + b2f((uint16_t)(xA.y & 0xffff));
    zf[3] = (float)zi[3]*m4[3] + b2f((uint16_t)(xA.y >> 16));
    float ig = sigf(zf[0]), fg = sigf(zf[1]), gg = tanh_(zf[2]), og = sigf(zf[3]);
    cst = fg*cst + ig*gg;
    float hj = og * tanh_(cst);
    if (ks == 0) {
      int q = (int)rintf(hj * 127.f);
      ((unsigned char*)&hs8[cur^1][0])[j] = (unsigned char)(q & 0xff);
      hout[((size_t)ts*BATCH + b)*512 + dir*256 + j] = __float2bfloat16(hj);
    }
    // raw barrier: drain LDS only; global loads/stores stay in flight
    __builtin_amdgcn_sched_barrier(0);
    asm volatile("s_waitcnt lgkmcnt(0)" ::: "memory");
    __builtin_amdgcn_sched_barrier(0);
    __builtin_amdgcn_s_barrier();
    __builtin_amdgcn_sched_barrier(0);
    xA = xB; xB = xC;
  }
}

// ---- output projection: emissions[t*64+b][j] = h . w_out[j+1] + b_out[j+1] ----
__global__ __launch_bounds__(256) void outproj(const __hip_bfloat16* __restrict__ hb,
    const float* __restrict__ w_out, const float* __restrict__ b_out,
    float* __restrict__ em){
  __shared__ float wsm[NT*512];
  __shared__ float bsm[NT];
  int tid = threadIdx.x;
  for (int i = tid; i < NT*512; i += 256) wsm[i] = w_out[512 + i];  // rows 1..9
  if (tid < NT) bsm[tid] = b_out[1 + tid];
  __syncthreads();
  int wave = tid >> 6, l = tid & 63;
  int m = blockIdx.x*4 + wave;
  const __hip_bfloat16* hp = hb + (size_t)m*512;
  float hv[8];
#pragma unroll
  for (int q = 0; q < 8; ++q) hv[q] = __bfloat162float(hp[l + 64*q]);
  for (int jj = 0; jj < NT; ++jj) {
    float p = 0.f;
#pragma unroll
    for (int q = 0; q < 8; ++q) p += hv[q]*wsm[jj*512 + 64*q + l];
    p = wredsum(p);
    if (l == 0) em[(size_t)m*NT + jj] = p + bsm[jj];
  }
}

// ---- CRF: one wave per batch item; lanes 0..8 hold the 9-state score ----
__global__ __launch_bounds__(64) void crf(const int* __restrict__ tags,
    const float* __restrict__ em, const float* __restrict__ start_t,
    const float* __restrict__ end_t, const float* __restrict__ trans,
    float* __restrict__ part){
  int b = blockIdx.x;
  int l = threadIdx.x;
  float np = 0.f;
  for (int t = l; t < S_LEN; t += 64) {
    int tg = tags[b*S_LEN + t] - 1;
    float e = em[(size_t)(t*BATCH + b)*NT + tg];
    float tr = (t == 0) ? start_t[tg] : trans[(tags[b*S_LEN + t - 1] - 1)*NT + tg];
    np += e + tr;
  }
  float num = wredsum(np);
  num += end_t[tags[b*S_LEN + S_LEN-1] - 1];
  int j = (l < NT) ? l : 0;
  float tj[NT];
#pragma unroll
  for (int i = 0; i < NT; ++i) tj[i] = trans[i*NT + j];
  float sc = start_t[j] + em[(size_t)b*NT + j];
  for (int t = 1; t < S_LEN; ++t) {
    float e = em[(size_t)(t*BATCH + b)*NT + j];
    float m = -1e30f;
    float vals[NT];
#pragma unroll
    for (int i = 0; i < NT; ++i) { float si = __shfl(sc, i); vals[i] = si + tj[i]; m = fmaxf(m, vals[i]); }
    float ssum = 0.f;
#pragma unroll
    for (int i = 0; i < NT; ++i) ssum += __expf(vals[i] - m);
    sc = e + m + __logf(ssum);
  }
  float vj = (l < NT) ? (sc + end_t[l]) : -1e30f;
  float mx = vj;
#pragma unroll
  for (int s2 = 32; s2 > 0; s2 >>= 1) mx = fmaxf(mx, __shfl_xor(mx, s2));
  float es = __expf(vj - mx);
  es = wredsum(es);
  if (l == 0) part[b] = num - (mx + __logf(es));
}

__global__ void finalize(const float* __restrict__ part, float* __restrict__ out){
  float v = part[threadIdx.x];
  v = wredsum(v);
  if (threadIdx.x == 0) out[0] = -(v / 64.f);
}

extern "C" void kernel_launch(void* const* d_in, const int* in_sizes, int n_in,
                              void* d_out, int out_size, void* d_ws, size_t ws_size,
                              hipStream_t stream) {
  (void)in_sizes; (void)n_in; (void)out_size; (void)ws_size;
  const int*   inputs  = (const int*)d_in[0];
  const int*   tags    = (const int*)d_in[1];
  const float* emb     = (const float*)d_in[3];
  const float* w_ih_f  = (const float*)d_in[4];
  const float* w_hh_f  = (const float*)d_in[5];
  const float* b_ih_f  = (const float*)d_in[6];
  const float* b_hh_f  = (const float*)d_in[7];
  const float* w_ih_b  = (const float*)d_in[8];
  const float* w_hh_b  = (const float*)d_in[9];
  const float* b_ih_b  = (const float*)d_in[10];
  const float* b_hh_b  = (const float*)d_in[11];
  const float* w_out   = (const float*)d_in[12];
  const float* b_out   = (const float*)d_in[13];
  const float* start_t = (const float*)d_in[14];
  const float* end_t   = (const float*)d_in[15];
  const float* trans   = (const float*)d_in[16];

  char* ws = (char*)d_ws;
  size_t off = 0;
  auto alloc = [&](size_t bytes) -> void* {
    void* p = ws + off;
    off = (off + bytes + 255) & ~(size_t)255;
    return p;
  };
  uint16_t* xgf = (uint16_t*)alloc((size_t)NTOK*1024*2);
  uint16_t* xgb = (uint16_t*)alloc((size_t)NTOK*1024*2);
  __hip_bfloat16* hbf = (__hip_bfloat16*)alloc((size_t)NTOK*512*2);
  float*    em    = (float*)alloc((size_t)NTOK*NT*4);
  uint16_t* wih16 = (uint16_t*)alloc((size_t)2048*256*2);
  float*    bias  = (float*)alloc((size_t)2048*4);
  float*    mult  = (float*)alloc((size_t)2048*4);
  uint32_t* wpk9  = (uint32_t*)alloc((size_t)2*64*1024*4);
  float*    part  = (float*)alloc((size_t)64*4);

  prep2<<<2048, 256, 0, stream>>>(w_ih_f, w_ih_b, b_ih_f, b_hh_f, b_ih_b, b_hh_b, wih16, bias);
  prep_scale<<<8, 256, 0, stream>>>(w_hh_f, w_hh_b, mult);
  prep_pack9<<<512, 256, 0, stream>>>(w_hh_f, w_hh_b, mult, wpk9);
  inproj_mfma<<<dim3(256, 16), 256, 0, stream>>>(inputs, emb, wih16, bias, xgf, xgb);
  lstm9<<<128, 1024, 0, stream>>>(wpk9, mult, xgf, xgb, hbf);
  outproj<<<4096, 256, 0, stream>>>(hbf, w_out, b_out, em);
  crf<<<64, 64, 0, stream>>>(tags, em, start_t, end_t, trans, part);
  finalize<<<1, 64, 0, stream>>>(part, (float*)d_out);
}

// Round 12
// 547.974 us; speedup vs baseline: 58.4461x; 1.0434x over previous
//
#include <hip/hip_runtime.h>
#include <hip/hip_bf16.h>
#include <stdint.h>

#define S_LEN 256
#define BATCH 64
#define HD 256
#define NT 9
#define NTOK (S_LEN*BATCH)   // 16384

typedef _Float16 hf2 __attribute__((ext_vector_type(2)));
typedef short bf16x8 __attribute__((ext_vector_type(8)));
typedef float f32x4 __attribute__((ext_vector_type(4)));

__device__ __forceinline__ float sigf(float x){ return 1.f/(1.f+__expf(-x)); }
__device__ __forceinline__ float tanh_(float x){ return 1.f - 2.f/(__expf(2.f*x)+1.f); }
__device__ __forceinline__ float wredsum(float v){
#pragma unroll
  for (int s = 32; s > 0; s >>= 1) v += __shfl_xor(v, s);
  return v;
}
__device__ __forceinline__ uint16_t f2b(float f){
  __hip_bfloat16 h = __float2bfloat16(f);
  return *(uint16_t*)&h;
}
__device__ __forceinline__ float b2f(uint16_t u){
  union{uint32_t i; float f;} a; a.i = ((uint32_t)u)<<16; return a.f;
}

__device__ __forceinline__ int sdot4(uint32_t a, uint32_t b, int c){
#if __has_builtin(__builtin_amdgcn_sdot4)
  return __builtin_amdgcn_sdot4((int)a, (int)b, c, false);
#else
  int r = c;
#pragma unroll
  for (int e = 0; e < 4; ++e) {
    int av = (int)(signed char)((a >> (8*e)) & 0xff);
    int bv = (int)(signed char)((b >> (8*e)) & 0xff);
    r += av * bv;
  }
  return r;
#endif
}

// quad reduce via DPP quad_perm (pure VALU; __shfl_xor may lower to LDS swizzle)
__device__ __forceinline__ int qadd_xor1(int v){
#if __has_builtin(__builtin_amdgcn_update_dpp)
  return v + __builtin_amdgcn_update_dpp(0, v, 0xB1, 0xF, 0xF, false); // [1,0,3,2]
#else
  return v + __shfl_xor(v, 1);
#endif
}
__device__ __forceinline__ int qadd_xor2(int v){
#if __has_builtin(__builtin_amdgcn_update_dpp)
  return v + __builtin_amdgcn_update_dpp(0, v, 0x4E, 0xF, 0xF, false); // [2,3,0,1]
#else
  return v + __shfl_xor(v, 2);
#endif
}

// ---- prep: wih16[n][k] = bf16(w_ih_dir[g][k]) (n = dir*1024+g); bias[n] = b_ih+b_hh ----
__global__ void prep2(const float* __restrict__ wihf, const float* __restrict__ wihb,
                      const float* __restrict__ bif, const float* __restrict__ bhf,
                      const float* __restrict__ bib, const float* __restrict__ bhb,
                      uint16_t* __restrict__ wih16, float* __restrict__ bias){
  int idx = blockIdx.x*256 + threadIdx.x;       // < 2048*256
  int n = idx >> 8;
  int k = idx & 255;
  const float* w = (n < 1024) ? wihf : wihb;
  int g = n & 1023;
  wih16[idx] = f2b(w[g*256 + k]);
  if (idx < 2048) {
    bias[idx] = (idx < 1024) ? (bif[idx] + bhf[idx]) : (bib[idx-1024] + bhb[idx-1024]);
  }
}

// ---- prep: gathered bf16 A-matrix: gemb[m][k] = bf16(emb[tok(m)][k]), m = t*64+b ----
__global__ void prep_gemb(const int* __restrict__ inp, const float* __restrict__ emb,
                          uint16_t* __restrict__ gemb){
  int idx = blockIdx.x*256 + threadIdx.x;   // < 16384*32
  int m = idx >> 5;
  int k8 = (idx & 31)*8;
  int tok = inp[(m & 63)*S_LEN + (m >> 6)];
  const float* src = emb + (size_t)tok*256 + k8;
  float4 v0 = *(const float4*)(src);
  float4 v1 = *(const float4*)(src+4);
  uint16_t t16[8];
  t16[0]=f2b(v0.x); t16[1]=f2b(v0.y); t16[2]=f2b(v0.z); t16[3]=f2b(v0.w);
  t16[4]=f2b(v1.x); t16[5]=f2b(v1.y); t16[6]=f2b(v1.z); t16[7]=f2b(v1.w);
  *(uint4*)&gemb[(size_t)m*256 + k8] = *(uint4*)t16;
}

// ---- prep: per-gate-column symmetric i8 scale: mult[dir*1024+c] = amax_c/(127*127) ----
__global__ void prep_scale(const float* __restrict__ whf, const float* __restrict__ whb,
                           float* __restrict__ mult){
  int idx = blockIdx.x*256 + threadIdx.x;   // < 2048
  int dir = idx >> 10, c = idx & 1023;
  const float* w = (dir ? whb : whf) + (size_t)c*256;
  float amax = 0.f;
  for (int k = 0; k < 256; ++k) amax = fmaxf(amax, fabsf(w[k]));
  mult[idx] = amax / 16129.f;   // = (amax/127) * (1/127)
}

// ---- prep: pack w_hh to i8x4 for lstm10's (j, ks) layout ----
__global__ void prep_pack9(const float* __restrict__ whf, const float* __restrict__ whb,
                           const float* __restrict__ mult, uint32_t* __restrict__ wpk9){
  int idx = blockIdx.x*256 + threadIdx.x;   // < 131072
  int dir = idx >> 16;
  int rem = idx & 65535;
  int r = rem >> 10;        // 0..63 = g*16 + p
  int tid = rem & 1023;
  int g = r >> 4, p = r & 15;
  int j = tid >> 2, ks = tid & 3;
  int col = g*256 + j;
  const float* w = (dir ? whb : whf) + (size_t)col*256 + ks*64 + p*4;
  float sw = mult[dir*1024 + col] * 127.f;
  float inv = (sw > 0.f) ? (1.f/sw) : 0.f;
  uint32_t pk = 0;
#pragma unroll
  for (int e = 0; e < 4; ++e) {
    float q = rintf(w[e] * inv);
    q = fminf(127.f, fmaxf(-127.f, q));
    int qi = (int)q;
    pk |= ((uint32_t)(qi & 0xff)) << (8*e);
  }
  wpk9[idx] = pk;
}

// ---- input projection via MFMA from pre-gathered bf16 A ----
__global__ __launch_bounds__(256) void inproj_mfma2(const uint16_t* __restrict__ gemb,
    const uint16_t* __restrict__ wih16, const float* __restrict__ bias,
    uint16_t* __restrict__ xgf, uint16_t* __restrict__ xgb){
  __shared__ uint16_t As[64][72];    // A[m][k] bf16, +8 pad
  __shared__ uint16_t Bs[128][72];   // B^T[c][k] = w_ih[n0+c][k] bf16, +8 pad
  int bm = blockIdx.x, bn = blockIdx.y;
  int tid = threadIdx.x;
  int w = tid >> 6, l = tid & 63;
  int lr = l & 15, lg = l >> 4;
  f32x4 acc[8];
#pragma unroll
  for (int cf = 0; cf < 8; ++cf) acc[cf] = (f32x4){0.f,0.f,0.f,0.f};

  int am = tid >> 2, aq = tid & 3;             // A staging: row am, 16 k each
  int bc = tid >> 1, bh = tid & 1;             // B staging: row bc, 32 k each

  for (int k0 = 0; k0 < 256; k0 += 64) {
    {
      const uint16_t* asrc = gemb + (size_t)(bm*64 + am)*256 + k0 + aq*16;
      uint4 a0 = *(const uint4*)(asrc);
      uint4 a1 = *(const uint4*)(asrc+8);
      *(uint4*)&As[am][aq*16]     = a0;
      *(uint4*)&As[am][aq*16 + 8] = a1;
    }
    {
      const uint16_t* bsrc = wih16 + (size_t)(bn*128 + bc)*256 + k0 + bh*32;
      uint4 b0 = *(const uint4*)(bsrc+0);
      uint4 b1 = *(const uint4*)(bsrc+8);
      uint4 b2 = *(const uint4*)(bsrc+16);
      uint4 b3 = *(const uint4*)(bsrc+24);
      *(uint4*)&Bs[bc][bh*32+0]  = b0;
      *(uint4*)&Bs[bc][bh*32+8]  = b1;
      *(uint4*)&Bs[bc][bh*32+16] = b2;
      *(uint4*)&Bs[bc][bh*32+24] = b3;
    }
    __syncthreads();
#pragma unroll
    for (int ks = 0; ks < 2; ++ks) {
      int koff = ks*32 + lg*8;
      bf16x8 a = *(const bf16x8*)&As[16*w + lr][koff];
#pragma unroll
      for (int cf = 0; cf < 8; ++cf) {
        bf16x8 b = *(const bf16x8*)&Bs[cf*16 + lr][koff];
        acc[cf] = __builtin_amdgcn_mfma_f32_16x16x32_bf16(a, b, acc[cf], 0, 0, 0);
      }
    }
    __syncthreads();
  }
  int n0 = bn*128;
  bool back = (n0 >= 1024);
  uint16_t* dst = back ? xgb : xgf;
  int nb0 = back ? (n0 - 1024) : n0;
#pragma unroll
  for (int cf = 0; cf < 8; ++cf) {
    int nc = cf*16 + lr;
    int nd = nb0 + nc;                 // within-dir column
    int gj = (nd & 255)*4 + (nd >> 8); // unit-major, gate-minor position
    float bv = bias[n0 + nc];
#pragma unroll
    for (int r = 0; r < 4; ++r) {
      int m = bm*64 + 16*w + lg*4 + r;
      dst[(size_t)m*1024 + gj] = f2b(acc[cf][r] + bv);
    }
  }
}

// ---- recurrence: one wg per (dir, batch); 1024 threads = (unit j, k-quarter ks) ----
// i8 dot4, weights reg-resident; quad reduce via DPP (VALU pipe, no LDS swizzle);
// raw s_barrier with lgkmcnt-only drain.
__global__ __launch_bounds__(1024, 4)
void lstm10(const uint32_t* __restrict__ wpk9, const float* __restrict__ mult,
    const uint16_t* __restrict__ xgf, const uint16_t* __restrict__ xgb,
    __hip_bfloat16* __restrict__ hout){
  int dir = blockIdx.x >> 6;
  int b = blockIdx.x & 63;
  int tid = threadIdx.x;
  int j = tid >> 2, ks = tid & 3;
  __shared__ __align__(16) uint32_t hs8[2][64];   // h as i8*127, double-buffered

  const uint32_t* wp = wpk9 + (size_t)dir*65536 + tid;
  uint32_t wreg[64];
#pragma unroll
  for (int r = 0; r < 64; ++r) wreg[r] = wp[r*1024];
#pragma unroll
  for (int r = 0; r < 64; ++r) asm volatile("" : "+v"(wreg[r]));
  asm volatile("" ::: "memory");

  float m4[4];
#pragma unroll
  for (int g = 0; g < 4; ++g) m4[g] = mult[dir*1024 + g*256 + j];

  if (tid < 128) hs8[tid >> 6][tid & 63] = 0u;
  float cst = 0.f;
  const uint16_t* xgp = (dir ? xgb : xgf) + (size_t)b*1024 + j*4;
  __syncthreads();

  int ts0 = dir ? (S_LEN-1) : 0;
  int ts1 = dir ? (S_LEN-2) : 1;
  uint2 xA = *(const uint2*)(xgp + (size_t)ts0*65536);   // depth-2 prefetch
  uint2 xB = *(const uint2*)(xgp + (size_t)ts1*65536);
  for (int t = 0; t < S_LEN; ++t) {
    int ts = dir ? (S_LEN-1-t) : t;
    int cur = t & 1;
    uint2 xC = xB;
    if (t + 2 < S_LEN) {
      int tn = dir ? (S_LEN-3-t) : (t+2);
      xC = *(const uint2*)(xgp + (size_t)tn*65536);
    }
    // h window: 16 dwords (64 i8) at dword ks*16
    const uint4* hp = (const uint4*)&hs8[cur][ks*16];
    uint4 h0 = hp[0], h1 = hp[1], h2 = hp[2], h3 = hp[3];
    int zi[4] = {0,0,0,0};
#pragma unroll
    for (int g = 0; g < 4; ++g) {
      const uint32_t* wg_ = &wreg[g*16];
      zi[g] = sdot4(wg_[0],  h0.x, zi[g]);
      zi[g] = sdot4(wg_[1],  h0.y, zi[g]);
      zi[g] = sdot4(wg_[2],  h0.z, zi[g]);
      zi[g] = sdot4(wg_[3],  h0.w, zi[g]);
      zi[g] = sdot4(wg_[4],  h1.x, zi[g]);
      zi[g] = sdot4(wg_[5],  h1.y, zi[g]);
      zi[g] = sdot4(wg_[6],  h1.z, zi[g]);
      zi[g] = sdot4(wg_[7],  h1.w, zi[g]);
      zi[g] = sdot4(wg_[8],  h2.x, zi[g]);
      zi[g] = sdot4(wg_[9],  h2.y, zi[g]);
      zi[g] = sdot4(wg_[10], h2.z, zi[g]);
      zi[g] = sdot4(wg_[11], h2.w, zi[g]);
      zi[g] = sdot4(wg_[12], h3.x, zi[g]);
      zi[g] = sdot4(wg_[13], h3.y, zi[g]);
      zi[g] = sdot4(wg_[14], h3.z, zi[g]);
      zi[g] = sdot4(wg_[15], h3.w, zi[g]);
    }
    // exact i32 quad reduce on the VALU pipe (DPP quad_perm)
#pragma unroll
    for (int g = 0; g < 4; ++g) zi[g] = qadd_xor1(zi[g]);
#pragma unroll
    for (int g = 0; g < 4; ++g) zi[g] = qadd_xor2(zi[g]);
    float zf[4];
    zf[0] = (float)zi[0]*m4[0] + b2f((uint16_t)(xA.x & 0xffff));
    zf[1] = (float)zi[1]*m4[1] + b2f((uint16_t)(xA.x >> 16));
    zf[2] = (float)zi[2]*m4[2] + b2f((uint16_t)(xA.y & 0xffff));
    zf[3] = (float)zi[3]*m4[3] + b2f((uint16_t)(xA.y >> 16));
    float ig = sigf(zf[0]), fg = sigf(zf[1]), gg = tanh_(zf[2]), og = sigf(zf[3]);
    cst = fg*cst + ig*gg;
    float hj = og * tanh_(cst);
    if (ks == 0) {
      int q = (int)rintf(hj * 127.f);
      ((unsigned char*)&hs8[cur^1][0])[j] = (unsigned char)(q & 0xff);
      hout[((size_t)ts*BATCH + b)*512 + dir*256 + j] = __float2bfloat16(hj);
    }
    // raw barrier: drain LDS only; global loads/stores stay in flight
    __builtin_amdgcn_sched_barrier(0);
    asm volatile("s_waitcnt lgkmcnt(0)" ::: "memory");
    __builtin_amdgcn_sched_barrier(0);
    __builtin_amdgcn_s_barrier();
    __builtin_amdgcn_sched_barrier(0);
    xA = xB; xB = xC;
  }
}

// ---- output projection: emissions[t*64+b][j] = h . w_out[j+1] + b_out[j+1] ----
__global__ __launch_bounds__(256) void outproj(const __hip_bfloat16* __restrict__ hb,
    const float* __restrict__ w_out, const float* __restrict__ b_out,
    float* __restrict__ em){
  __shared__ float wsm[NT*512];
  __shared__ float bsm[NT];
  int tid = threadIdx.x;
  for (int i = tid; i < NT*512; i += 256) wsm[i] = w_out[512 + i];  // rows 1..9
  if (tid < NT) bsm[tid] = b_out[1 + tid];
  __syncthreads();
  int wave = tid >> 6, l = tid & 63;
  int m = blockIdx.x*4 + wave;
  const __hip_bfloat16* hp = hb + (size_t)m*512;
  float hv[8];
#pragma unroll
  for (int q = 0; q < 8; ++q) hv[q] = __bfloat162float(hp[l + 64*q]);
  for (int jj = 0; jj < NT; ++jj) {
    float p = 0.f;
#pragma unroll
    for (int q = 0; q < 8; ++q) p += hv[q]*wsm[jj*512 + 64*q + l];
    p = wredsum(p);
    if (l == 0) em[(size_t)m*NT + jj] = p + bsm[jj];
  }
}

// ---- CRF: one wave per batch item; lanes 0..8 hold the 9-state score ----
__global__ __launch_bounds__(64) void crf(const int* __restrict__ tags,
    const float* __restrict__ em, const float* __restrict__ start_t,
    const float* __restrict__ end_t, const float* __restrict__ trans,
    float* __restrict__ part){
  int b = blockIdx.x;
  int l = threadIdx.x;
  float np = 0.f;
  for (int t = l; t < S_LEN; t += 64) {
    int tg = tags[b*S_LEN + t] - 1;
    float e = em[(size_t)(t*BATCH + b)*NT + tg];
    float tr = (t == 0) ? start_t[tg] : trans[(tags[b*S_LEN + t - 1] - 1)*NT + tg];
    np += e + tr;
  }
  float num = wredsum(np);
  num += end_t[tags[b*S_LEN + S_LEN-1] - 1];
  int j = (l < NT) ? l : 0;
  float tj[NT];
#pragma unroll
  for (int i = 0; i < NT; ++i) tj[i] = trans[i*NT + j];
  float sc = start_t[j] + em[(size_t)b*NT + j];
  for (int t = 1; t < S_LEN; ++t) {
    float e = em[(size_t)(t*BATCH + b)*NT + j];
    float m = -1e30f;
    float vals[NT];
#pragma unroll
    for (int i = 0; i < NT; ++i) { float si = __shfl(sc, i); vals[i] = si + tj[i]; m = fmaxf(m, vals[i]); }
    float ssum = 0.f;
#pragma unroll
    for (int i = 0; i < NT; ++i) ssum += __expf(vals[i] - m);
    sc = e + m + __logf(ssum);
  }
  float vj = (l < NT) ? (sc + end_t[l]) : -1e30f;
  float mx = vj;
#pragma unroll
  for (int s2 = 32; s2 > 0; s2 >>= 1) mx = fmaxf(mx, __shfl_xor(mx, s2));
  float es = __expf(vj - mx);
  es = wredsum(es);
  if (l == 0) part[b] = num - (mx + __logf(es));
}

__global__ void finalize(const float* __restrict__ part, float* __restrict__ out){
  float v = part[threadIdx.x];
  v = wredsum(v);
  if (threadIdx.x == 0) out[0] = -(v / 64.f);
}

extern "C" void kernel_launch(void* const* d_in, const int* in_sizes, int n_in,
                              void* d_out, int out_size, void* d_ws, size_t ws_size,
                              hipStream_t stream) {
  (void)in_sizes; (void)n_in; (void)out_size; (void)ws_size;
  const int*   inputs  = (const int*)d_in[0];
  const int*   tags    = (const int*)d_in[1];
  const float* emb     = (const float*)d_in[3];
  const float* w_ih_f  = (const float*)d_in[4];
  const float* w_hh_f  = (const float*)d_in[5];
  const float* b_ih_f  = (const float*)d_in[6];
  const float* b_hh_f  = (const float*)d_in[7];
  const float* w_ih_b  = (const float*)d_in[8];
  const float* w_hh_b  = (const float*)d_in[9];
  const float* b_ih_b  = (const float*)d_in[10];
  const float* b_hh_b  = (const float*)d_in[11];
  const float* w_out   = (const float*)d_in[12];
  const float* b_out   = (const float*)d_in[13];
  const float* start_t = (const float*)d_in[14];
  const float* end_t   = (const float*)d_in[15];
  const float* trans   = (const float*)d_in[16];

  char* ws = (char*)d_ws;
  size_t off = 0;
  auto alloc = [&](size_t bytes) -> void* {
    void* p = ws + off;
    off = (off + bytes + 255) & ~(size_t)255;
    return p;
  };
  uint16_t* xgf = (uint16_t*)alloc((size_t)NTOK*1024*2);
  uint16_t* xgb = (uint16_t*)alloc((size_t)NTOK*1024*2);
  __hip_bfloat16* hbf = (__hip_bfloat16*)alloc((size_t)NTOK*512*2);
  float*    em    = (float*)alloc((size_t)NTOK*NT*4);
  uint16_t* wih16 = (uint16_t*)alloc((size_t)2048*256*2);
  uint16_t* gemb  = (uint16_t*)alloc((size_t)NTOK*256*2);
  float*    bias  = (float*)alloc((size_t)2048*4);
  float*    mult  = (float*)alloc((size_t)2048*4);
  uint32_t* wpk9  = (uint32_t*)alloc((size_t)2*64*1024*4);
  float*    part  = (float*)alloc((size_t)64*4);

  prep2<<<2048, 256, 0, stream>>>(w_ih_f, w_ih_b, b_ih_f, b_hh_f, b_ih_b, b_hh_b, wih16, bias);
  prep_gemb<<<2048, 256, 0, stream>>>(inputs, emb, gemb);
  prep_scale<<<8, 256, 0, stream>>>(w_hh_f, w_hh_b, mult);
  prep_pack9<<<512, 256, 0, stream>>>(w_hh_f, w_hh_b, mult, wpk9);
  inproj_mfma2<<<dim3(256, 16), 256, 0, stream>>>(gemb, wih16, bias, xgf, xgb);
  lstm10<<<128, 1024, 0, stream>>>(wpk9, mult, xgf, xgb, hbf);
  outproj<<<4096, 256, 0, stream>>>(hbf, w_out, b_out, em);
  crf<<<64, 64, 0, stream>>>(tags, em, start_t, end_t, trans, part);
  finalize<<<1, 64, 0, stream>>>(part, (float*)d_out);
}